// Round 5
// baseline (385.400 us; speedup 1.0000x reference)
//
#include <hip/hip_runtime.h>

// Problem constants (fixed by reference)
#define IN_DIM  256
#define HID_DIM 256
#define H2_DIM  128
#define EMB_DIM 64
#define K_CODES 4096
#define EPS_BN  1e-5f

// R5: argmin on matrix pipe via fp16 hi/lo split (3 passes) -> 205us.
// R6: fused encoder. 295us. R7: fragment-major packing; NULL (grid-capped).
// R8: argmin 8 waves, occupancy 21->42%, dur FLAT. Occupancy theory REFUTED.
// R9: barrier-free L2 streaming, FLAT 126us. Staging-structure REFUTED.
// R10: reg double-buffer prefetch: REGRESSED 178us (VGPR 80, compiler
// serialized both buffers' waitcnts). REVERTED.
// Invariant across R7-R9 (~120us, MfmaUtil 37-39%): B-fragment bytes per
// output row. 8KB fragments feed only 32 rows x 32 cols; per-CU port
// (LDS or VMEM, similar effective rate) saturates. R11: 2 ROW-TILES PER
// WAVE — one B-fragment set feeds 24 MFMAs / 64 rows; per-row fragment
// traffic and latency exposure halve. 256thr/4waves/128rows, grid 512
// (2 blocks/CU barrier overlap preserved). Same MFMA visit order and
// compare trajectory -> absmax 0. Publish buffers stride-33 padded
// (R8's 590k bank conflicts were the stride-16 publish).

typedef _Float16 f16;
typedef _Float16 f16x4 __attribute__((ext_vector_type(4)));
typedef _Float16 f16x8 __attribute__((ext_vector_type(8)));
typedef float    f32x16 __attribute__((ext_vector_type(16)));

// ---------------------------------------------------------------------------
// Kernel 0a: half squared norms of codebook rows: norms[c] = 0.5*||e_c||^2
// ---------------------------------------------------------------------------
__global__ __launch_bounds__(256) void k_norms(const float* __restrict__ cb,
                                               float* __restrict__ norms) {
    int c = blockIdx.x * 256 + threadIdx.x;
    const float4* row = reinterpret_cast<const float4*>(cb + (size_t)c * EMB_DIM);
    float s = 0.f;
#pragma unroll
    for (int i = 0; i < EMB_DIM / 4; ++i) {
        float4 v = row[i];
        s += v.x * v.x + v.y * v.y + v.z * v.z + v.w * v.w;
    }
    norms[c] = 0.5f * s;
}

// ---------------------------------------------------------------------------
// Kernel 0b: fragment-major hi/lo packer.
// A fragment = 512 f16 = what one wave loads for one (k16-step, 32-col-tile):
//   P[f*512 + l*8 + j] = W[ct*32 + (l&31)][k0 + (l>>5)*8 + j]
// f16x8 unit index t (one thread each), 46080 total:
//   [0,8192)      W1 [256][256]: f = kst*8 + ct   (kst<16, ct<8)
//   [8192,12288)  W2 [128][256]: f = kst*4 + ct   (kst<16, ct<4)
//   [12288,13312) W3 [ 64][128]: f = ks*2  + ct   (ks<8, ct<2)
//   [13312,46080) cb [4096][64]: f = (ch*4+ks)*4+ct (ch<32, ks<4, ct<4)
// ---------------------------------------------------------------------------
__global__ __launch_bounds__(256) void k_prep(
    const float* __restrict__ W1, const float* __restrict__ W2,
    const float* __restrict__ W3, const float* __restrict__ cb,
    f16* __restrict__ p1h, f16* __restrict__ p1l,
    f16* __restrict__ p2h, f16* __restrict__ p2l,
    f16* __restrict__ p3h, f16* __restrict__ p3l,
    f16* __restrict__ cfh, f16* __restrict__ cfl) {
    int t = blockIdx.x * 256 + threadIdx.x;   // < 46080
    const float* src; f16 *dh, *dl; int tt, row, k0, K;
    if (t < 8192) {
        tt = t; int f = tt >> 6, l = tt & 63;
        int ct = f & 7, kst = f >> 3;
        row = ct * 32 + (l & 31); k0 = kst * 16 + (l >> 5) * 8;
        src = W1; K = IN_DIM; dh = p1h; dl = p1l;
    } else if (t < 12288) {
        tt = t - 8192; int f = tt >> 6, l = tt & 63;
        int ct = f & 3, kst = f >> 2;
        row = ct * 32 + (l & 31); k0 = kst * 16 + (l >> 5) * 8;
        src = W2; K = HID_DIM; dh = p2h; dl = p2l;
    } else if (t < 13312) {
        tt = t - 12288; int f = tt >> 6, l = tt & 63;
        int ct = f & 1, ks = f >> 1;
        row = ct * 32 + (l & 31); k0 = ks * 16 + (l >> 5) * 8;
        src = W3; K = H2_DIM; dh = p3h; dl = p3l;
    } else {
        tt = t - 13312; int f = tt >> 6, l = tt & 63;
        int ct = f & 3, ks = (f >> 2) & 3, ch = f >> 4;
        row = ch * 128 + ct * 32 + (l & 31); k0 = ks * 16 + (l >> 5) * 8;
        src = cb; K = EMB_DIM; dh = cfh; dl = cfl;
    }
    const float* s = src + (size_t)row * K + k0;
    f16x8 hv, lv;
#pragma unroll
    for (int j = 0; j < 8; ++j) {
        float v = s[j];
        f16 h = (f16)v;
        hv[j] = h;
        lv[j] = (f16)(v - (float)h);
    }
    *(f16x8*)(dh + (size_t)tt * 8) = hv;
    *(f16x8*)(dl + (size_t)tt * 8) = lv;
}

// ---------------------------------------------------------------------------
// Kernel 1: fused MFMA encoder. 32 rows/block, 256 threads (4 waves).
// All GEMMs as v_mfma_f32_32x32x16_f16, 3 passes (hh, lh, hl) per k-step.
// A-frags from LDS (stride 264/136 f16); B-frags streamed from fragment-major
// global with 1-deep register prefetch. LDS 51.2 KB -> 3 blocks/CU. 4 barriers.
// ---------------------------------------------------------------------------
__global__ __launch_bounds__(256) void k_encoder_mfma(
    const float* __restrict__ x,
    const f16* __restrict__ p1h, const f16* __restrict__ p1l,
    const f16* __restrict__ p2h, const f16* __restrict__ p2l,
    const f16* __restrict__ p3h, const f16* __restrict__ p3l,
    const float* __restrict__ b1,
    const float* __restrict__ gm, const float* __restrict__ bt,
    const float* __restrict__ mu, const float* __restrict__ vr,
    const float* __restrict__ b2, const float* __restrict__ b3,
    f16* __restrict__ Zh, f16* __restrict__ Zl) {
    __shared__ __align__(16) f16 sm[25600];
    const int tid  = threadIdx.x;
    const int lane = tid & 63;
    const int w    = tid >> 6;
    const int ln31 = lane & 31;
    const int q    = lane >> 5;
    const int r0   = blockIdx.x * 32;

    // ---- stage x [32 rows][256 k] fp32 -> hi/lo f16 planes, once ----------
#pragma unroll
    for (int it = 0; it < 8; ++it) {
        int i = it * 256 + tid;              // float4 id, 2048 total
        int row = i >> 6, c4 = (i & 63) * 4;
        float4 v = *reinterpret_cast<const float4*>(
            x + (size_t)(r0 + row) * IN_DIM + c4);
        f16x4 hv, lv;
        hv[0] = (f16)v.x; lv[0] = (f16)(v.x - (float)hv[0]);
        hv[1] = (f16)v.y; lv[1] = (f16)(v.y - (float)hv[1]);
        hv[2] = (f16)v.z; lv[2] = (f16)(v.z - (float)hv[2]);
        hv[3] = (f16)v.w; lv[3] = (f16)(v.w - (float)hv[3]);
        *(f16x4*)(sm + row * 264 + c4)        = hv;
        *(f16x4*)(sm + 8448 + row * 264 + c4) = lv;
    }
    __syncthreads();

    // ================= Stage 1: h1 = BN+ReLU(x @ W1^T) ======================
    f32x16 acc1a = {};
    f32x16 acc1b = {};
    {
        const f16* q1h = p1h + (size_t)(2 * w) * 512 + lane * 8;
        const f16* q1l = p1l + (size_t)(2 * w) * 512 + lane * 8;
        f16x8 bh0 = *(const f16x8*)(q1h);
        f16x8 bh1 = *(const f16x8*)(q1h + 512);
        f16x8 bl0 = *(const f16x8*)(q1l);
        f16x8 bl1 = *(const f16x8*)(q1l + 512);
#pragma unroll 2
        for (int kst = 0; kst < 16; ++kst) {
            f16x8 ch0 = bh0, ch1 = bh1, cl0 = bl0, cl1 = bl1;
            int kn = (kst + 1) & 15;  // wrap: last prefetch redundant, harmless
            bh0 = *(const f16x8*)(q1h + (size_t)kn * 4096);
            bh1 = *(const f16x8*)(q1h + (size_t)kn * 4096 + 512);
            bl0 = *(const f16x8*)(q1l + (size_t)kn * 4096);
            bl1 = *(const f16x8*)(q1l + (size_t)kn * 4096 + 512);
            int koff = kst * 16 + q * 8;
            f16x8 ah = *(const f16x8*)(sm + ln31 * 264 + koff);
            f16x8 al = *(const f16x8*)(sm + 8448 + ln31 * 264 + koff);
            acc1a = __builtin_amdgcn_mfma_f32_32x32x16_f16(ah, ch0, acc1a, 0, 0, 0);
            acc1b = __builtin_amdgcn_mfma_f32_32x32x16_f16(ah, ch1, acc1b, 0, 0, 0);
            acc1a = __builtin_amdgcn_mfma_f32_32x32x16_f16(al, ch0, acc1a, 0, 0, 0);
            acc1b = __builtin_amdgcn_mfma_f32_32x32x16_f16(al, ch1, acc1b, 0, 0, 0);
            acc1a = __builtin_amdgcn_mfma_f32_32x32x16_f16(ah, cl0, acc1a, 0, 0, 0);
            acc1b = __builtin_amdgcn_mfma_f32_32x32x16_f16(ah, cl1, acc1b, 0, 0, 0);
        }
    }
    __syncthreads();  // all x reads done; region A becomes h1 planes

    // BN + ReLU epilogue; write h1 hi/lo planes (stride 264).
    {
#pragma unroll
        for (int nt = 0; nt < 2; ++nt) {
            int j = w * 64 + nt * 32 + ln31;
            float sc = gm[j] * rsqrtf(vr[j] + EPS_BN);
            float sh = (b1[j] - mu[j]) * sc + bt[j];
            const f32x16& a = nt ? acc1b : acc1a;
#pragma unroll
            for (int r = 0; r < 16; ++r) {
                int row = (r & 3) + 8 * (r >> 2) + 4 * q;
                float v = a[r] * sc + sh;
                v = v > 0.f ? v : 0.f;
                f16 h = (f16)v;
                sm[row * 264 + j]        = h;
                sm[8448 + row * 264 + j] = (f16)(v - (float)h);
            }
        }
    }
    __syncthreads();  // h1 ready

    // ================= Stage 2: h2 = ReLU(h1 @ W2^T + b2) ===================
    f32x16 acc2a = {};
    f32x16 acc2b = {};
    {
        const f16* q2h = p2h + (size_t)w * 512 + lane * 8;
        const f16* q2l = p2l + (size_t)w * 512 + lane * 8;
        f16x8 bh = *(const f16x8*)(q2h);
        f16x8 bl = *(const f16x8*)(q2l);
#pragma unroll 2
        for (int kst = 0; kst < 16; ++kst) {
            f16x8 cbh = bh, cbl = bl;
            int kn = (kst + 1) & 15;
            bh = *(const f16x8*)(q2h + (size_t)kn * 2048);
            bl = *(const f16x8*)(q2l + (size_t)kn * 2048);
            int koff = kst * 16 + q * 8;
            f16x8 ah = *(const f16x8*)(sm + ln31 * 264 + koff);
            f16x8 al = *(const f16x8*)(sm + 8448 + ln31 * 264 + koff);
            f32x16& acc = (kst & 1) ? acc2b : acc2a;
            acc = __builtin_amdgcn_mfma_f32_32x32x16_f16(ah, cbh, acc, 0, 0, 0);
            acc = __builtin_amdgcn_mfma_f32_32x32x16_f16(al, cbh, acc, 0, 0, 0);
            acc = __builtin_amdgcn_mfma_f32_32x32x16_f16(ah, cbl, acc, 0, 0, 0);
        }
    }
    // ReLU epilogue -> h2 planes in region B.
    {
        int j2 = w * 32 + ln31;
        float bias = b2[j2];
#pragma unroll
        for (int r = 0; r < 16; ++r) {
            int row = (r & 3) + 8 * (r >> 2) + 4 * q;
            float v = (acc2a[r] + acc2b[r]) + bias;
            v = v > 0.f ? v : 0.f;
            f16 h = (f16)v;
            sm[16896 + row * 136 + j2] = h;
            sm[21248 + row * 136 + j2] = (f16)(v - (float)h);
        }
    }
    __syncthreads();  // h2 ready

    // ================= Stage 3: z = tanh(h2 @ W3^T + b3) ====================
    if (w < 2) {  // 64 output cols -> waves 0,1 only
        f32x16 acc3a = {};
        f32x16 acc3b = {};
        const f16* q3h = p3h + (size_t)w * 512 + lane * 8;
        const f16* q3l = p3l + (size_t)w * 512 + lane * 8;
        f16x8 bh = *(const f16x8*)(q3h);
        f16x8 bl = *(const f16x8*)(q3l);
#pragma unroll 2
        for (int ks = 0; ks < 8; ++ks) {
            f16x8 cbh = bh, cbl = bl;
            int kn = (ks + 1) & 7;
            bh = *(const f16x8*)(q3h + (size_t)kn * 1024);
            bl = *(const f16x8*)(q3l + (size_t)kn * 1024);
            f16x8 ah = *(const f16x8*)(sm + 16896 + ln31 * 136 + ks * 16 + q * 8);
            f16x8 al = *(const f16x8*)(sm + 21248 + ln31 * 136 + ks * 16 + q * 8);
            f32x16& acc = (ks & 1) ? acc3b : acc3a;
            acc = __builtin_amdgcn_mfma_f32_32x32x16_f16(ah, cbh, acc, 0, 0, 0);
            acc = __builtin_amdgcn_mfma_f32_32x32x16_f16(al, cbh, acc, 0, 0, 0);
            acc = __builtin_amdgcn_mfma_f32_32x32x16_f16(ah, cbl, acc, 0, 0, 0);
        }
        int j3 = w * 32 + ln31;
        float bias = b3[j3];
#pragma unroll
        for (int r = 0; r < 16; ++r) {
            int row = (r & 3) + 8 * (r >> 2) + 4 * q;
            float zv = tanhf((acc3a[r] + acc3b[r]) + bias);
            f16 h = (f16)zv;
            size_t idx = (size_t)(r0 + row) * EMB_DIM + j3;
            Zh[idx] = h;
            Zl[idx] = (f16)(zv - (float)h);
        }
    }
}

// ---------------------------------------------------------------------------
// Kernel 2: MFMA argmin. 128 rows/block, 256 threads (4 waves), 2 row-tiles
// per wave. Wave w: rg = w&1 (rows rg*64..rg*64+63), hp = w>>1 (ct pair).
// Per chunk: stage 32KB codebook frags to LDS (shared by all 4 waves); per
// ct, ONE B-fragment read feeds BOTH row-tiles (24 MFMAs) — per-row LDS/VMEM
// fragment traffic halved vs R8. Same per-cell visit order -> absmax 0.
// score(r,c) = z_r.e_c - 0.5||e_c||^2, maximized == argmin distance.
// ---------------------------------------------------------------------------
__global__ __launch_bounds__(256) void k_argmin_mfma(
    const f16* __restrict__ Zh, const f16* __restrict__ Zl,
    const f16* __restrict__ cfh, const f16* __restrict__ cfl,
    const float* __restrict__ norms, int* __restrict__ out) {
    __shared__ __align__(16) f16 sm[16896];  // 33.8 KB
    f16* ebh = sm;                   // 16 frags x 512 f16 (one 128-code chunk)
    f16* ebl = sm + 8192;
    float* nbuf = (float*)(sm + 16384);  // [128]
    const int tid  = threadIdx.x;
    const int lane = tid & 63;
    const int w    = tid >> 6;      // 0..3
    const int rg   = w & 1;         // row-group of 64 (2 row-tiles)
    const int hp   = w >> 1;        // ct-pair half
    const int ln31 = lane & 31;
    const int q    = lane >> 5;
    const int r0   = blockIdx.x * 128;

    // z fragments for BOTH row-tiles of this wave's row-group.
    f16x8 ah0[4], al0[4], ah1[4], al1[4];
#pragma unroll
    for (int ks = 0; ks < 4; ++ks) {
        size_t za = (size_t)(r0 + rg * 64 + ln31) * EMB_DIM + ks * 16 + q * 8;
        size_t zb = za + (size_t)32 * EMB_DIM;
        ah0[ks] = *(const f16x8*)(Zh + za);
        al0[ks] = *(const f16x8*)(Zl + za);
        ah1[ks] = *(const f16x8*)(Zh + zb);
        al1[ks] = *(const f16x8*)(Zl + zb);
    }

    float bv0[16], bv1[16];
    int   bi0[16], bi1[16];
#pragma unroll
    for (int i = 0; i < 16; ++i) {
        bv0[i] = -3.4e38f; bi0[i] = 0;
        bv1[i] = -3.4e38f; bi1[i] = 0;
    }

#pragma unroll 1
    for (int ch = 0; ch < K_CODES / 128; ++ch) {
        __syncthreads();
        // stage chunk: 2 x 16 KB, lane-linear (coalesced + conflict-free)
        const float4* sh = (const float4*)(cfh + (size_t)ch * 8192);
        const float4* sl = (const float4*)(cfl + (size_t)ch * 8192);
        float4* dh = (float4*)ebh;
        float4* dl = (float4*)ebl;
#pragma unroll
        for (int it = 0; it < 4; ++it) {
            dh[it * 256 + tid] = sh[it * 256 + tid];
            dl[it * 256 + tid] = sl[it * 256 + tid];
        }
        if (tid < 128) nbuf[tid] = norms[ch * 128 + tid];
        __syncthreads();

#pragma unroll 1
        for (int c2 = 0; c2 < 2; ++c2) {
            int ct = hp * 2 + c2;
            f16x8 bh[4], bl[4];
#pragma unroll
            for (int ks = 0; ks < 4; ++ks) {
                int off = (ks * 4 + ct) * 512 + lane * 8;
                bh[ks] = *(const f16x8*)(ebh + off);
                bl[ks] = *(const f16x8*)(ebl + off);
            }
            float nv  = nbuf[ct * 32 + ln31];
            int   col = ch * 128 + ct * 32 + ln31;
            // ---- row-tile 0 ----
            {
                f32x16 acc0 = {};
                f32x16 acc1 = {};
#pragma unroll
                for (int ks = 0; ks < 4; ks += 2) {
                    acc0 = __builtin_amdgcn_mfma_f32_32x32x16_f16(ah0[ks],     bh[ks],     acc0, 0, 0, 0);
                    acc1 = __builtin_amdgcn_mfma_f32_32x32x16_f16(ah0[ks + 1], bh[ks + 1], acc1, 0, 0, 0);
                    acc0 = __builtin_amdgcn_mfma_f32_32x32x16_f16(al0[ks],     bh[ks],     acc0, 0, 0, 0);
                    acc1 = __builtin_amdgcn_mfma_f32_32x32x16_f16(al0[ks + 1], bh[ks + 1], acc1, 0, 0, 0);
                    acc0 = __builtin_amdgcn_mfma_f32_32x32x16_f16(ah0[ks],     bl[ks],     acc0, 0, 0, 0);
                    acc1 = __builtin_amdgcn_mfma_f32_32x32x16_f16(ah0[ks + 1], bl[ks + 1], acc1, 0, 0, 0);
                }
#pragma unroll
                for (int r = 0; r < 16; ++r) {
                    float t  = (acc0[r] + acc1[r]) - nv;
                    bool  gt = t > bv0[r];
                    bv0[r] = gt ? t : bv0[r];
                    bi0[r] = gt ? col : bi0[r];
                }
            }
            // ---- row-tile 1 ----
            {
                f32x16 acc0 = {};
                f32x16 acc1 = {};
#pragma unroll
                for (int ks = 0; ks < 4; ks += 2) {
                    acc0 = __builtin_amdgcn_mfma_f32_32x32x16_f16(ah1[ks],     bh[ks],     acc0, 0, 0, 0);
                    acc1 = __builtin_amdgcn_mfma_f32_32x32x16_f16(ah1[ks + 1], bh[ks + 1], acc1, 0, 0, 0);
                    acc0 = __builtin_amdgcn_mfma_f32_32x32x16_f16(al1[ks],     bh[ks],     acc0, 0, 0, 0);
                    acc1 = __builtin_amdgcn_mfma_f32_32x32x16_f16(al1[ks + 1], bh[ks + 1], acc1, 0, 0, 0);
                    acc0 = __builtin_amdgcn_mfma_f32_32x32x16_f16(ah1[ks],     bl[ks],     acc0, 0, 0, 0);
                    acc1 = __builtin_amdgcn_mfma_f32_32x32x16_f16(ah1[ks + 1], bl[ks + 1], acc1, 0, 0, 0);
                }
#pragma unroll
                for (int r = 0; r < 16; ++r) {
                    float t  = (acc0[r] + acc1[r]) - nv;
                    bool  gt = t > bv1[r];
                    bv1[r] = gt ? t : bv1[r];
                    bi1[r] = gt ? col : bi1[r];
                }
            }
        }
    }

    // ---- merge ct-halves: waves hp=1 publish, hp=0 partners combine -------
    // pv: [rg][lane][33] floats (stride-33 pad -> conflict-free), 16896 B;
    // pi ints after, 16896 B. Total exactly 33792 B.
    __syncthreads();
    {
        float* pv = (float*)sm;
        int*   pi = (int*)sm + 4224;
        if (hp == 1) {
#pragma unroll
            for (int r = 0; r < 16; ++r) {
                pv[rg * 2112 + lane * 33 + r]      = bv0[r];
                pi[rg * 2112 + lane * 33 + r]      = bi0[r];
                pv[rg * 2112 + lane * 33 + 16 + r] = bv1[r];
                pi[rg * 2112 + lane * 33 + 16 + r] = bi1[r];
            }
        }
        __syncthreads();
        if (hp == 0) {
#pragma unroll
            for (int r = 0; r < 16; ++r) {
                float v2 = pv[rg * 2112 + lane * 33 + r];
                int   i2 = pi[rg * 2112 + lane * 33 + r];
                bool tk = (v2 > bv0[r]) || (v2 == bv0[r] && i2 < bi0[r]);
                bv0[r] = tk ? v2 : bv0[r];
                bi0[r] = tk ? i2 : bi0[r];
                float v3 = pv[rg * 2112 + lane * 33 + 16 + r];
                int   i3 = pi[rg * 2112 + lane * 33 + 16 + r];
                bool tk1 = (v3 > bv1[r]) || (v3 == bv1[r] && i3 < bi1[r]);
                bv1[r] = tk1 ? v3 : bv1[r];
                bi1[r] = tk1 ? i3 : bi1[r];
            }
        }
    }
    __syncthreads();  // partner-buffer reads done before redv overwrites

    // ---- cross-lane reduction over 32 code-columns ------------------------
    float* redv = (float*)sm;                // [128][33] f32, bytes [0,16896)
    int*   redi = (int*)sm + 4224;           // [128][33] i32, bytes [16896,33792)
    if (hp == 0) {
#pragma unroll
        for (int r = 0; r < 16; ++r) {
            int rowm = (r & 3) + 8 * (r >> 2) + 4 * q;
            int row0 = rg * 64 + rowm;
            int row1 = rg * 64 + 32 + rowm;
            redv[row0 * 33 + ln31] = bv0[r];
            redi[row0 * 33 + ln31] = bi0[r];
            redv[row1 * 33 + ln31] = bv1[r];
            redi[row1 * 33 + ln31] = bi1[r];
        }
    }
    __syncthreads();
    if (tid < 128) {
        float v  = redv[tid * 33];
        int   ix = redi[tid * 33];
#pragma unroll
        for (int j = 1; j < 32; ++j) {
            float vj = redv[tid * 33 + j];
            int   ij = redi[tid * 33 + j];
            if (vj > v || (vj == v && ij < ix)) { v = vj; ix = ij; }
        }
        out[r0 + tid] = ix;
    }
}

// ---------------------------------------------------------------------------
extern "C" void kernel_launch(void* const* d_in, const int* in_sizes, int n_in,
                              void* d_out, int out_size, void* d_ws, size_t ws_size,
                              hipStream_t stream) {
    (void)n_in; (void)out_size; (void)ws_size;
    const float* x  = (const float*)d_in[0];
    const float* W1 = (const float*)d_in[1];
    const float* b1 = (const float*)d_in[2];
    const float* gm = (const float*)d_in[3];
    const float* bt = (const float*)d_in[4];
    const float* mu = (const float*)d_in[5];
    const float* vr = (const float*)d_in[6];
    const float* W2 = (const float*)d_in[7];
    const float* b2 = (const float*)d_in[8];
    const float* W3 = (const float*)d_in[9];
    const float* b3 = (const float*)d_in[10];
    const float* cb = (const float*)d_in[11];

    // Workspace layout (~17.4 MB) — same offsets as R6/R7
    char* ws = (char*)d_ws;
    float* norms = (float*)ws;                    // 16 KB
    f16* cfh = (f16*)(ws + 16384);                // 512 KB (cb frags hi)
    f16* cfl = (f16*)(ws + 540672);               // 512 KB (cb frags lo)
    f16* p1h = (f16*)(ws + 1064960);              // 128 KB
    f16* p1l = (f16*)(ws + 1196032);              // 128 KB
    f16* p2h = (f16*)(ws + 1327104);              // 64 KB
    f16* p2l = (f16*)(ws + 1392640);              // 64 KB
    f16* p3h = (f16*)(ws + 1458176);              // 16 KB
    f16* p3l = (f16*)(ws + 1474560);              // 16 KB
    f16* Zh  = (f16*)(ws + 1490944);              // 8 MB
    f16* Zl  = (f16*)(ws + 9879552);              // 8 MB
    int* out = (int*)d_out;

    const int B = in_sizes[0] / IN_DIM;  // 65536

    k_norms<<<K_CODES / 256, 256, 0, stream>>>(cb, norms);
    k_prep<<<180, 256, 0, stream>>>(W1, W2, W3, cb, p1h, p1l, p2h, p2l,
                                    p3h, p3l, cfh, cfl);
    k_encoder_mfma<<<B / 32, 256, 0, stream>>>(x, p1h, p1l, p2h, p2l, p3h, p3l,
                                               b1, gm, bt, mu, vr, b2, b3, Zh, Zl);
    k_argmin_mfma<<<B / 128, 256, 0, stream>>>(Zh, Zl, cfh, cfl, norms, out);
}

// Round 6
// 306.639 us; speedup vs baseline: 1.2569x; 1.2569x over previous
//
#include <hip/hip_runtime.h>

// Problem constants (fixed by reference)
#define IN_DIM  256
#define HID_DIM 256
#define H2_DIM  128
#define EMB_DIM 64
#define K_CODES 4096
#define EPS_BN  1e-5f

// R5: argmin on matrix pipe via fp16 hi/lo split (3 passes) -> 205us.
// R6: fused encoder. 295us. R7: fragment-major packing; NULL (grid-capped).
// R8: argmin 8 waves lockstep: occupancy 21->42%, dur FLAT. (Lockstep
// structure wastes the extra waves at barriers.)
// R9: barrier-free L2 streaming, 4 waves/SIMD: 126us, MfmaUtil 37%.
// MFMA floor is 41us; per-iter wall 1181cyc vs 384 MFMA + ~400 VALU ->
// latency-bound at LOW occupancy (grid 512 capped 16 waves/CU).
// R10: reg double-buffer: REGRESSED (VGPR 80, serialized waitcnts).
// R11: 2 row-tiles/wave: REGRESSED (VGPR 136, occupancy 11.5%).
// R12: R9 body + grid 1024 x 512thr (64 rows/block, wave = rt x ct-quarter)
// -> 4 blocks/CU = 32 waves/CU = 8 waves/SIMD, VGPR unchanged (~64).
// Fixed ct per wave -> constant-stride addressing. 3-round LDS merge tree
// (stride-17 pad). Bit-identical per-cell math -> absmax 0.
// Expected wall: L2 BW (~2GB/34.5TBps = 58us) || MFMA 41us.

typedef _Float16 f16;
typedef _Float16 f16x4 __attribute__((ext_vector_type(4)));
typedef _Float16 f16x8 __attribute__((ext_vector_type(8)));
typedef float    f32x16 __attribute__((ext_vector_type(16)));

// ---------------------------------------------------------------------------
// Kernel 0a: half squared norms of codebook rows: norms[c] = 0.5*||e_c||^2
// ---------------------------------------------------------------------------
__global__ __launch_bounds__(256) void k_norms(const float* __restrict__ cb,
                                               float* __restrict__ norms) {
    int c = blockIdx.x * 256 + threadIdx.x;
    const float4* row = reinterpret_cast<const float4*>(cb + (size_t)c * EMB_DIM);
    float s = 0.f;
#pragma unroll
    for (int i = 0; i < EMB_DIM / 4; ++i) {
        float4 v = row[i];
        s += v.x * v.x + v.y * v.y + v.z * v.z + v.w * v.w;
    }
    norms[c] = 0.5f * s;
}

// ---------------------------------------------------------------------------
// Kernel 0b: fragment-major hi/lo packer.
// A fragment = 512 f16 = what one wave loads for one (k16-step, 32-col-tile):
//   P[f*512 + l*8 + j] = W[ct*32 + (l&31)][k0 + (l>>5)*8 + j]
// f16x8 unit index t (one thread each), 46080 total:
//   [0,8192)      W1 [256][256]: f = kst*8 + ct   (kst<16, ct<8)
//   [8192,12288)  W2 [128][256]: f = kst*4 + ct   (kst<16, ct<4)
//   [12288,13312) W3 [ 64][128]: f = ks*2  + ct   (ks<8, ct<2)
//   [13312,46080) cb [4096][64]: f = (ch*4+ks)*4+ct (ch<32, ks<4, ct<4)
// ---------------------------------------------------------------------------
__global__ __launch_bounds__(256) void k_prep(
    const float* __restrict__ W1, const float* __restrict__ W2,
    const float* __restrict__ W3, const float* __restrict__ cb,
    f16* __restrict__ p1h, f16* __restrict__ p1l,
    f16* __restrict__ p2h, f16* __restrict__ p2l,
    f16* __restrict__ p3h, f16* __restrict__ p3l,
    f16* __restrict__ cfh, f16* __restrict__ cfl) {
    int t = blockIdx.x * 256 + threadIdx.x;   // < 46080
    const float* src; f16 *dh, *dl; int tt, row, k0, K;
    if (t < 8192) {
        tt = t; int f = tt >> 6, l = tt & 63;
        int ct = f & 7, kst = f >> 3;
        row = ct * 32 + (l & 31); k0 = kst * 16 + (l >> 5) * 8;
        src = W1; K = IN_DIM; dh = p1h; dl = p1l;
    } else if (t < 12288) {
        tt = t - 8192; int f = tt >> 6, l = tt & 63;
        int ct = f & 3, kst = f >> 2;
        row = ct * 32 + (l & 31); k0 = kst * 16 + (l >> 5) * 8;
        src = W2; K = HID_DIM; dh = p2h; dl = p2l;
    } else if (t < 13312) {
        tt = t - 12288; int f = tt >> 6, l = tt & 63;
        int ct = f & 1, ks = f >> 1;
        row = ct * 32 + (l & 31); k0 = ks * 16 + (l >> 5) * 8;
        src = W3; K = H2_DIM; dh = p3h; dl = p3l;
    } else {
        tt = t - 13312; int f = tt >> 6, l = tt & 63;
        int ct = f & 3, ks = (f >> 2) & 3, ch = f >> 4;
        row = ch * 128 + ct * 32 + (l & 31); k0 = ks * 16 + (l >> 5) * 8;
        src = cb; K = EMB_DIM; dh = cfh; dl = cfl;
    }
    const float* s = src + (size_t)row * K + k0;
    f16x8 hv, lv;
#pragma unroll
    for (int j = 0; j < 8; ++j) {
        float v = s[j];
        f16 h = (f16)v;
        hv[j] = h;
        lv[j] = (f16)(v - (float)h);
    }
    *(f16x8*)(dh + (size_t)tt * 8) = hv;
    *(f16x8*)(dl + (size_t)tt * 8) = lv;
}

// ---------------------------------------------------------------------------
// Kernel 1: fused MFMA encoder. 32 rows/block, 256 threads (4 waves).
// All GEMMs as v_mfma_f32_32x32x16_f16, 3 passes (hh, lh, hl) per k-step.
// A-frags from LDS (stride 264/136 f16); B-frags streamed from fragment-major
// global with 1-deep register prefetch. LDS 51.2 KB -> 3 blocks/CU. 4 barriers.
// ---------------------------------------------------------------------------
__global__ __launch_bounds__(256) void k_encoder_mfma(
    const float* __restrict__ x,
    const f16* __restrict__ p1h, const f16* __restrict__ p1l,
    const f16* __restrict__ p2h, const f16* __restrict__ p2l,
    const f16* __restrict__ p3h, const f16* __restrict__ p3l,
    const float* __restrict__ b1,
    const float* __restrict__ gm, const float* __restrict__ bt,
    const float* __restrict__ mu, const float* __restrict__ vr,
    const float* __restrict__ b2, const float* __restrict__ b3,
    f16* __restrict__ Zh, f16* __restrict__ Zl) {
    __shared__ __align__(16) f16 sm[25600];
    const int tid  = threadIdx.x;
    const int lane = tid & 63;
    const int w    = tid >> 6;
    const int ln31 = lane & 31;
    const int q    = lane >> 5;
    const int r0   = blockIdx.x * 32;

    // ---- stage x [32 rows][256 k] fp32 -> hi/lo f16 planes, once ----------
#pragma unroll
    for (int it = 0; it < 8; ++it) {
        int i = it * 256 + tid;              // float4 id, 2048 total
        int row = i >> 6, c4 = (i & 63) * 4;
        float4 v = *reinterpret_cast<const float4*>(
            x + (size_t)(r0 + row) * IN_DIM + c4);
        f16x4 hv, lv;
        hv[0] = (f16)v.x; lv[0] = (f16)(v.x - (float)hv[0]);
        hv[1] = (f16)v.y; lv[1] = (f16)(v.y - (float)hv[1]);
        hv[2] = (f16)v.z; lv[2] = (f16)(v.z - (float)hv[2]);
        hv[3] = (f16)v.w; lv[3] = (f16)(v.w - (float)hv[3]);
        *(f16x4*)(sm + row * 264 + c4)        = hv;
        *(f16x4*)(sm + 8448 + row * 264 + c4) = lv;
    }
    __syncthreads();

    // ================= Stage 1: h1 = BN+ReLU(x @ W1^T) ======================
    f32x16 acc1a = {};
    f32x16 acc1b = {};
    {
        const f16* q1h = p1h + (size_t)(2 * w) * 512 + lane * 8;
        const f16* q1l = p1l + (size_t)(2 * w) * 512 + lane * 8;
        f16x8 bh0 = *(const f16x8*)(q1h);
        f16x8 bh1 = *(const f16x8*)(q1h + 512);
        f16x8 bl0 = *(const f16x8*)(q1l);
        f16x8 bl1 = *(const f16x8*)(q1l + 512);
#pragma unroll 2
        for (int kst = 0; kst < 16; ++kst) {
            f16x8 ch0 = bh0, ch1 = bh1, cl0 = bl0, cl1 = bl1;
            int kn = (kst + 1) & 15;  // wrap: last prefetch redundant, harmless
            bh0 = *(const f16x8*)(q1h + (size_t)kn * 4096);
            bh1 = *(const f16x8*)(q1h + (size_t)kn * 4096 + 512);
            bl0 = *(const f16x8*)(q1l + (size_t)kn * 4096);
            bl1 = *(const f16x8*)(q1l + (size_t)kn * 4096 + 512);
            int koff = kst * 16 + q * 8;
            f16x8 ah = *(const f16x8*)(sm + ln31 * 264 + koff);
            f16x8 al = *(const f16x8*)(sm + 8448 + ln31 * 264 + koff);
            acc1a = __builtin_amdgcn_mfma_f32_32x32x16_f16(ah, ch0, acc1a, 0, 0, 0);
            acc1b = __builtin_amdgcn_mfma_f32_32x32x16_f16(ah, ch1, acc1b, 0, 0, 0);
            acc1a = __builtin_amdgcn_mfma_f32_32x32x16_f16(al, ch0, acc1a, 0, 0, 0);
            acc1b = __builtin_amdgcn_mfma_f32_32x32x16_f16(al, ch1, acc1b, 0, 0, 0);
            acc1a = __builtin_amdgcn_mfma_f32_32x32x16_f16(ah, cl0, acc1a, 0, 0, 0);
            acc1b = __builtin_amdgcn_mfma_f32_32x32x16_f16(ah, cl1, acc1b, 0, 0, 0);
        }
    }
    __syncthreads();  // all x reads done; region A becomes h1 planes

    // BN + ReLU epilogue; write h1 hi/lo planes (stride 264).
    {
#pragma unroll
        for (int nt = 0; nt < 2; ++nt) {
            int j = w * 64 + nt * 32 + ln31;
            float sc = gm[j] * rsqrtf(vr[j] + EPS_BN);
            float sh = (b1[j] - mu[j]) * sc + bt[j];
            const f32x16& a = nt ? acc1b : acc1a;
#pragma unroll
            for (int r = 0; r < 16; ++r) {
                int row = (r & 3) + 8 * (r >> 2) + 4 * q;
                float v = a[r] * sc + sh;
                v = v > 0.f ? v : 0.f;
                f16 h = (f16)v;
                sm[row * 264 + j]        = h;
                sm[8448 + row * 264 + j] = (f16)(v - (float)h);
            }
        }
    }
    __syncthreads();  // h1 ready

    // ================= Stage 2: h2 = ReLU(h1 @ W2^T + b2) ===================
    f32x16 acc2a = {};
    f32x16 acc2b = {};
    {
        const f16* q2h = p2h + (size_t)w * 512 + lane * 8;
        const f16* q2l = p2l + (size_t)w * 512 + lane * 8;
        f16x8 bh = *(const f16x8*)(q2h);
        f16x8 bl = *(const f16x8*)(q2l);
#pragma unroll 2
        for (int kst = 0; kst < 16; ++kst) {
            f16x8 cbh = bh, cbl = bl;
            int kn = (kst + 1) & 15;
            bh = *(const f16x8*)(q2h + (size_t)kn * 2048);
            bl = *(const f16x8*)(q2l + (size_t)kn * 2048);
            int koff = kst * 16 + q * 8;
            f16x8 ah = *(const f16x8*)(sm + ln31 * 264 + koff);
            f16x8 al = *(const f16x8*)(sm + 8448 + ln31 * 264 + koff);
            f32x16& acc = (kst & 1) ? acc2b : acc2a;
            acc = __builtin_amdgcn_mfma_f32_32x32x16_f16(ah, cbh, acc, 0, 0, 0);
            acc = __builtin_amdgcn_mfma_f32_32x32x16_f16(al, cbh, acc, 0, 0, 0);
            acc = __builtin_amdgcn_mfma_f32_32x32x16_f16(ah, cbl, acc, 0, 0, 0);
        }
    }
    // ReLU epilogue -> h2 planes in region B.
    {
        int j2 = w * 32 + ln31;
        float bias = b2[j2];
#pragma unroll
        for (int r = 0; r < 16; ++r) {
            int row = (r & 3) + 8 * (r >> 2) + 4 * q;
            float v = (acc2a[r] + acc2b[r]) + bias;
            v = v > 0.f ? v : 0.f;
            f16 h = (f16)v;
            sm[16896 + row * 136 + j2] = h;
            sm[21248 + row * 136 + j2] = (f16)(v - (float)h);
        }
    }
    __syncthreads();  // h2 ready

    // ================= Stage 3: z = tanh(h2 @ W3^T + b3) ====================
    if (w < 2) {  // 64 output cols -> waves 0,1 only
        f32x16 acc3a = {};
        f32x16 acc3b = {};
        const f16* q3h = p3h + (size_t)w * 512 + lane * 8;
        const f16* q3l = p3l + (size_t)w * 512 + lane * 8;
        f16x8 bh = *(const f16x8*)(q3h);
        f16x8 bl = *(const f16x8*)(q3l);
#pragma unroll 2
        for (int ks = 0; ks < 8; ++ks) {
            f16x8 cbh = bh, cbl = bl;
            int kn = (ks + 1) & 7;
            bh = *(const f16x8*)(q3h + (size_t)kn * 1024);
            bl = *(const f16x8*)(q3l + (size_t)kn * 1024);
            f16x8 ah = *(const f16x8*)(sm + 16896 + ln31 * 136 + ks * 16 + q * 8);
            f16x8 al = *(const f16x8*)(sm + 21248 + ln31 * 136 + ks * 16 + q * 8);
            f32x16& acc = (ks & 1) ? acc3b : acc3a;
            acc = __builtin_amdgcn_mfma_f32_32x32x16_f16(ah, cbh, acc, 0, 0, 0);
            acc = __builtin_amdgcn_mfma_f32_32x32x16_f16(al, cbh, acc, 0, 0, 0);
            acc = __builtin_amdgcn_mfma_f32_32x32x16_f16(ah, cbl, acc, 0, 0, 0);
        }
        int j3 = w * 32 + ln31;
        float bias = b3[j3];
#pragma unroll
        for (int r = 0; r < 16; ++r) {
            int row = (r & 3) + 8 * (r >> 2) + 4 * q;
            float zv = tanhf((acc3a[r] + acc3b[r]) + bias);
            f16 h = (f16)zv;
            size_t idx = (size_t)(r0 + row) * EMB_DIM + j3;
            Zh[idx] = h;
            Zl[idx] = (f16)(zv - (float)h);
        }
    }
}

// ---------------------------------------------------------------------------
// Kernel 2: MFMA argmin. 64 rows/block, 512 threads (8 waves), grid 1024
// -> 4 blocks/CU = 32 waves/CU = 8 waves/SIMD (VGPR ~64).
// Wave w: rt = w&1 (row-tile), hp = w>>1 (fixed ct-quarter). Each wave
// streams 32 iters (ch ascending, ct=hp) barrier-free from L2:
//   frag(ch,ks,hp) at ((ch*16 + ks*4 + hp)*512 + lane*8)  — constant
//   8192-f16 stride per ch -> cheap addressing.
// score(r,c) = z_r.e_c - 0.5||e_c||^2, maximized == argmin distance.
// Per-cell math, MFMA operand order, visit order bit-identical to R9.
// Merge: 3-round LDS tree (hp=1,2,3 publish; hp=0 combines; stride-17 pad),
// explicit lowest-index tie-break == reference first-occurrence argmin.
// ---------------------------------------------------------------------------
__global__ __launch_bounds__(512) void k_argmin_mfma(
    const f16* __restrict__ Zh, const f16* __restrict__ Zl,
    const f16* __restrict__ cfh, const f16* __restrict__ cfl,
    const float* __restrict__ norms, int* __restrict__ out) {
    __shared__ __align__(16) float smf[4352];   // 17408 B
    const int tid  = threadIdx.x;
    const int lane = tid & 63;
    const int w    = tid >> 6;      // 0..7
    const int rt   = w & 1;         // row-tile (2 per block)
    const int hp   = w >> 1;        // ct-quarter (0..3), fixed per wave
    const int ln31 = lane & 31;
    const int q    = lane >> 5;
    const int r0   = blockIdx.x * 64;

    // z fragments: 8 x 16B per lane, straight from global (row-major Z).
    // 4 hp-waves share each row-tile (duplicate read, L2-served).
    f16x8 ah[4], al[4];
#pragma unroll
    for (int ks = 0; ks < 4; ++ks) {
        size_t zoff = (size_t)(r0 + rt * 32 + ln31) * EMB_DIM + ks * 16 + q * 8;
        ah[ks] = *(const f16x8*)(Zh + zoff);
        al[ks] = *(const f16x8*)(Zl + zoff);
    }

    float bv[16];
    int   bi[16];
#pragma unroll
    for (int i = 0; i < 16; ++i) { bv[i] = -3.4e38f; bi[i] = 0; }

#pragma unroll 1
    for (int ch = 0; ch < 32; ++ch) {
        size_t fb = (size_t)(ch * 16 + hp) * 512 + lane * 8;
        f16x8 bh[4], bl[4];
#pragma unroll
        for (int ks = 0; ks < 4; ++ks) {
            bh[ks] = *(const f16x8*)(cfh + fb + (size_t)ks * 2048);
            bl[ks] = *(const f16x8*)(cfl + fb + (size_t)ks * 2048);
        }
        f32x16 acc0 = {};
        f32x16 acc1 = {};
#pragma unroll
        for (int ks = 0; ks < 4; ks += 2) {
            acc0 = __builtin_amdgcn_mfma_f32_32x32x16_f16(ah[ks],     bh[ks],     acc0, 0, 0, 0);
            acc1 = __builtin_amdgcn_mfma_f32_32x32x16_f16(ah[ks + 1], bh[ks + 1], acc1, 0, 0, 0);
            acc0 = __builtin_amdgcn_mfma_f32_32x32x16_f16(al[ks],     bh[ks],     acc0, 0, 0, 0);
            acc1 = __builtin_amdgcn_mfma_f32_32x32x16_f16(al[ks + 1], bh[ks + 1], acc1, 0, 0, 0);
            acc0 = __builtin_amdgcn_mfma_f32_32x32x16_f16(ah[ks],     bl[ks],     acc0, 0, 0, 0);
            acc1 = __builtin_amdgcn_mfma_f32_32x32x16_f16(ah[ks + 1], bl[ks + 1], acc1, 0, 0, 0);
        }
        int   col = ch * 128 + hp * 32 + ln31;
        float nv  = norms[col];
#pragma unroll
        for (int r = 0; r < 16; ++r) {
            float t  = (acc0[r] + acc1[r]) - nv;
            bool  gt = t > bv[r];
            bv[r] = gt ? t : bv[r];
            bi[r] = gt ? col : bi[r];
        }
    }

    // ---- 3-round merge tree over hp: publish buffer [2][64][17] padded ----
    float* pv = smf;                       // [2][64][17] f32
    int*   pi = (int*)smf + 2176;          // [2][64][17] i32
#pragma unroll 1
    for (int k = 1; k < 4; ++k) {
        __syncthreads();
        if (hp == k) {
#pragma unroll
            for (int r = 0; r < 16; ++r) {
                pv[rt * 1088 + lane * 17 + r] = bv[r];
                pi[rt * 1088 + lane * 17 + r] = bi[r];
            }
        }
        __syncthreads();
        if (hp == 0) {
#pragma unroll
            for (int r = 0; r < 16; ++r) {
                float v2 = pv[rt * 1088 + lane * 17 + r];
                int   i2 = pi[rt * 1088 + lane * 17 + r];
                // lowest-index-on-tie == reference argmin (first occurrence)
                bool tk = (v2 > bv[r]) || (v2 == bv[r] && i2 < bi[r]);
                bv[r] = tk ? v2 : bv[r];
                bi[r] = tk ? i2 : bi[r];
            }
        }
    }
    __syncthreads();  // publish-buffer reads done before redv overwrites

    // ---- cross-lane reduction over 32 code-columns ------------------------
    float* redv = smf;                     // [64][33] f32
    int*   redi = (int*)smf + 2112;        // [64][33] i32
    if (hp == 0) {
#pragma unroll
        for (int r = 0; r < 16; ++r) {
            int row = rt * 32 + (r & 3) + 8 * (r >> 2) + 4 * q;
            redv[row * 33 + ln31] = bv[r];
            redi[row * 33 + ln31] = bi[r];
        }
    }
    __syncthreads();
    if (tid < 64) {
        float v  = redv[tid * 33];
        int   ix = redi[tid * 33];
#pragma unroll
        for (int j = 1; j < 32; ++j) {
            float vj = redv[tid * 33 + j];
            int   ij = redi[tid * 33 + j];
            if (vj > v || (vj == v && ij < ix)) { v = vj; ix = ij; }
        }
        out[r0 + tid] = ix;
    }
}

// ---------------------------------------------------------------------------
extern "C" void kernel_launch(void* const* d_in, const int* in_sizes, int n_in,
                              void* d_out, int out_size, void* d_ws, size_t ws_size,
                              hipStream_t stream) {
    (void)n_in; (void)out_size; (void)ws_size;
    const float* x  = (const float*)d_in[0];
    const float* W1 = (const float*)d_in[1];
    const float* b1 = (const float*)d_in[2];
    const float* gm = (const float*)d_in[3];
    const float* bt = (const float*)d_in[4];
    const float* mu = (const float*)d_in[5];
    const float* vr = (const float*)d_in[6];
    const float* W2 = (const float*)d_in[7];
    const float* b2 = (const float*)d_in[8];
    const float* W3 = (const float*)d_in[9];
    const float* b3 = (const float*)d_in[10];
    const float* cb = (const float*)d_in[11];

    // Workspace layout (~17.4 MB) — same offsets as R6/R7
    char* ws = (char*)d_ws;
    float* norms = (float*)ws;                    // 16 KB
    f16* cfh = (f16*)(ws + 16384);                // 512 KB (cb frags hi)
    f16* cfl = (f16*)(ws + 540672);               // 512 KB (cb frags lo)
    f16* p1h = (f16*)(ws + 1064960);              // 128 KB
    f16* p1l = (f16*)(ws + 1196032);              // 128 KB
    f16* p2h = (f16*)(ws + 1327104);              // 64 KB
    f16* p2l = (f16*)(ws + 1392640);              // 64 KB
    f16* p3h = (f16*)(ws + 1458176);              // 16 KB
    f16* p3l = (f16*)(ws + 1474560);              // 16 KB
    f16* Zh  = (f16*)(ws + 1490944);              // 8 MB
    f16* Zl  = (f16*)(ws + 9879552);              // 8 MB
    int* out = (int*)d_out;

    const int B = in_sizes[0] / IN_DIM;  // 65536

    k_norms<<<K_CODES / 256, 256, 0, stream>>>(cb, norms);
    k_prep<<<180, 256, 0, stream>>>(W1, W2, W3, cb, p1h, p1l, p2h, p2l,
                                    p3h, p3l, cfh, cfl);
    k_encoder_mfma<<<B / 32, 256, 0, stream>>>(x, p1h, p1l, p2h, p2l, p3h, p3l,
                                               b1, gm, bt, mu, vr, b2, b3, Zh, Zl);
    k_argmin_mfma<<<B / 64, 512, 0, stream>>>(Zh, Zl, cfh, cfl, norms, out);
}

// Round 7
// 281.603 us; speedup vs baseline: 1.3686x; 1.0889x over previous
//
#include <hip/hip_runtime.h>

// Problem constants (fixed by reference)
#define IN_DIM  256
#define HID_DIM 256
#define H2_DIM  128
#define EMB_DIM 64
#define K_CODES 4096
#define EPS_BN  1e-5f

// R5: argmin on matrix pipe via fp16 hi/lo split (3 passes) -> 205us.
// R6: fused encoder. R7: fragment-major packing. R8: 8-wave lockstep
// (occupancy theory refuted). R9: barrier-free L2 streaming, 126us,
// MfmaUtil 37% (latency-bound). R10: reg double-buffer REGRESSED (VGPR/
// waitcnt serialization). R11: 2 row-tiles/wave REGRESSED (VGPR 136,
// occupancy 11.5%). R12: grid 1024 REGRESSED-vs-R9 (149us): Occupancy
// FLAT 40% — 64 VGPR + 32 AGPR = 96/wave caps 5 waves/SIMD; 512-thr WG
// can only fit 2/CU. TLP lever exhausted.
// R13: the R7 idea done right (T3-minimum pipeline):
//   - global_load_lds DMA staging (no VGPR round-trip, no ALU);
//   - stage(chunk t+1) issued BEFORE compute(chunk t): DMA lands under
//     the ~2000-cyc compute phase; __syncthreads() drains vmcnt (m97);
//   - each wave owns one row-tile and consumes ALL 4 ct from the shared
//     chunk -> codebook L2 traffic 2.1GB -> 0.5GB (4x), and the ct-merge
//     tree disappears (only the 32-lane column reduction remains).
// Visit order (ch asc, ct asc) and per-cell math identical -> absmax 0.
// LDS 64KB (2 x 32KB dbuf) -> 2 blocks/CU; grid 512 x 256thr.

typedef _Float16 f16;
typedef _Float16 f16x4 __attribute__((ext_vector_type(4)));
typedef _Float16 f16x8 __attribute__((ext_vector_type(8)));
typedef float    f32x16 __attribute__((ext_vector_type(16)));

// ---------------------------------------------------------------------------
// Kernel 0a: half squared norms of codebook rows: norms[c] = 0.5*||e_c||^2
// ---------------------------------------------------------------------------
__global__ __launch_bounds__(256) void k_norms(const float* __restrict__ cb,
                                               float* __restrict__ norms) {
    int c = blockIdx.x * 256 + threadIdx.x;
    const float4* row = reinterpret_cast<const float4*>(cb + (size_t)c * EMB_DIM);
    float s = 0.f;
#pragma unroll
    for (int i = 0; i < EMB_DIM / 4; ++i) {
        float4 v = row[i];
        s += v.x * v.x + v.y * v.y + v.z * v.z + v.w * v.w;
    }
    norms[c] = 0.5f * s;
}

// ---------------------------------------------------------------------------
// Kernel 0b: fragment-major hi/lo packer.
// A fragment = 512 f16 = what one wave loads for one (k16-step, 32-col-tile):
//   P[f*512 + l*8 + j] = W[ct*32 + (l&31)][k0 + (l>>5)*8 + j]
// f16x8 unit index t (one thread each), 46080 total:
//   [0,8192)      W1 [256][256]: f = kst*8 + ct   (kst<16, ct<8)
//   [8192,12288)  W2 [128][256]: f = kst*4 + ct   (kst<16, ct<4)
//   [12288,13312) W3 [ 64][128]: f = ks*2  + ct   (ks<8, ct<2)
//   [13312,46080) cb [4096][64]: f = (ch*4+ks)*4+ct (ch<32, ks<4, ct<4)
// ---------------------------------------------------------------------------
__global__ __launch_bounds__(256) void k_prep(
    const float* __restrict__ W1, const float* __restrict__ W2,
    const float* __restrict__ W3, const float* __restrict__ cb,
    f16* __restrict__ p1h, f16* __restrict__ p1l,
    f16* __restrict__ p2h, f16* __restrict__ p2l,
    f16* __restrict__ p3h, f16* __restrict__ p3l,
    f16* __restrict__ cfh, f16* __restrict__ cfl) {
    int t = blockIdx.x * 256 + threadIdx.x;   // < 46080
    const float* src; f16 *dh, *dl; int tt, row, k0, K;
    if (t < 8192) {
        tt = t; int f = tt >> 6, l = tt & 63;
        int ct = f & 7, kst = f >> 3;
        row = ct * 32 + (l & 31); k0 = kst * 16 + (l >> 5) * 8;
        src = W1; K = IN_DIM; dh = p1h; dl = p1l;
    } else if (t < 12288) {
        tt = t - 8192; int f = tt >> 6, l = tt & 63;
        int ct = f & 3, kst = f >> 2;
        row = ct * 32 + (l & 31); k0 = kst * 16 + (l >> 5) * 8;
        src = W2; K = HID_DIM; dh = p2h; dl = p2l;
    } else if (t < 13312) {
        tt = t - 12288; int f = tt >> 6, l = tt & 63;
        int ct = f & 1, ks = f >> 1;
        row = ct * 32 + (l & 31); k0 = ks * 16 + (l >> 5) * 8;
        src = W3; K = H2_DIM; dh = p3h; dl = p3l;
    } else {
        tt = t - 13312; int f = tt >> 6, l = tt & 63;
        int ct = f & 3, ks = (f >> 2) & 3, ch = f >> 4;
        row = ch * 128 + ct * 32 + (l & 31); k0 = ks * 16 + (l >> 5) * 8;
        src = cb; K = EMB_DIM; dh = cfh; dl = cfl;
    }
    const float* s = src + (size_t)row * K + k0;
    f16x8 hv, lv;
#pragma unroll
    for (int j = 0; j < 8; ++j) {
        float v = s[j];
        f16 h = (f16)v;
        hv[j] = h;
        lv[j] = (f16)(v - (float)h);
    }
    *(f16x8*)(dh + (size_t)tt * 8) = hv;
    *(f16x8*)(dl + (size_t)tt * 8) = lv;
}

// ---------------------------------------------------------------------------
// Kernel 1: fused MFMA encoder. 32 rows/block, 256 threads (4 waves).
// All GEMMs as v_mfma_f32_32x32x16_f16, 3 passes (hh, lh, hl) per k-step.
// A-frags from LDS (stride 264/136 f16); B-frags streamed from fragment-major
// global with 1-deep register prefetch. LDS 51.2 KB -> 3 blocks/CU. 4 barriers.
// ---------------------------------------------------------------------------
__global__ __launch_bounds__(256) void k_encoder_mfma(
    const float* __restrict__ x,
    const f16* __restrict__ p1h, const f16* __restrict__ p1l,
    const f16* __restrict__ p2h, const f16* __restrict__ p2l,
    const f16* __restrict__ p3h, const f16* __restrict__ p3l,
    const float* __restrict__ b1,
    const float* __restrict__ gm, const float* __restrict__ bt,
    const float* __restrict__ mu, const float* __restrict__ vr,
    const float* __restrict__ b2, const float* __restrict__ b3,
    f16* __restrict__ Zh, f16* __restrict__ Zl) {
    __shared__ __align__(16) f16 sm[25600];
    const int tid  = threadIdx.x;
    const int lane = tid & 63;
    const int w    = tid >> 6;
    const int ln31 = lane & 31;
    const int q    = lane >> 5;
    const int r0   = blockIdx.x * 32;

    // ---- stage x [32 rows][256 k] fp32 -> hi/lo f16 planes, once ----------
#pragma unroll
    for (int it = 0; it < 8; ++it) {
        int i = it * 256 + tid;              // float4 id, 2048 total
        int row = i >> 6, c4 = (i & 63) * 4;
        float4 v = *reinterpret_cast<const float4*>(
            x + (size_t)(r0 + row) * IN_DIM + c4);
        f16x4 hv, lv;
        hv[0] = (f16)v.x; lv[0] = (f16)(v.x - (float)hv[0]);
        hv[1] = (f16)v.y; lv[1] = (f16)(v.y - (float)hv[1]);
        hv[2] = (f16)v.z; lv[2] = (f16)(v.z - (float)hv[2]);
        hv[3] = (f16)v.w; lv[3] = (f16)(v.w - (float)hv[3]);
        *(f16x4*)(sm + row * 264 + c4)        = hv;
        *(f16x4*)(sm + 8448 + row * 264 + c4) = lv;
    }
    __syncthreads();

    // ================= Stage 1: h1 = BN+ReLU(x @ W1^T) ======================
    f32x16 acc1a = {};
    f32x16 acc1b = {};
    {
        const f16* q1h = p1h + (size_t)(2 * w) * 512 + lane * 8;
        const f16* q1l = p1l + (size_t)(2 * w) * 512 + lane * 8;
        f16x8 bh0 = *(const f16x8*)(q1h);
        f16x8 bh1 = *(const f16x8*)(q1h + 512);
        f16x8 bl0 = *(const f16x8*)(q1l);
        f16x8 bl1 = *(const f16x8*)(q1l + 512);
#pragma unroll 2
        for (int kst = 0; kst < 16; ++kst) {
            f16x8 ch0 = bh0, ch1 = bh1, cl0 = bl0, cl1 = bl1;
            int kn = (kst + 1) & 15;  // wrap: last prefetch redundant, harmless
            bh0 = *(const f16x8*)(q1h + (size_t)kn * 4096);
            bh1 = *(const f16x8*)(q1h + (size_t)kn * 4096 + 512);
            bl0 = *(const f16x8*)(q1l + (size_t)kn * 4096);
            bl1 = *(const f16x8*)(q1l + (size_t)kn * 4096 + 512);
            int koff = kst * 16 + q * 8;
            f16x8 ah = *(const f16x8*)(sm + ln31 * 264 + koff);
            f16x8 al = *(const f16x8*)(sm + 8448 + ln31 * 264 + koff);
            acc1a = __builtin_amdgcn_mfma_f32_32x32x16_f16(ah, ch0, acc1a, 0, 0, 0);
            acc1b = __builtin_amdgcn_mfma_f32_32x32x16_f16(ah, ch1, acc1b, 0, 0, 0);
            acc1a = __builtin_amdgcn_mfma_f32_32x32x16_f16(al, ch0, acc1a, 0, 0, 0);
            acc1b = __builtin_amdgcn_mfma_f32_32x32x16_f16(al, ch1, acc1b, 0, 0, 0);
            acc1a = __builtin_amdgcn_mfma_f32_32x32x16_f16(ah, cl0, acc1a, 0, 0, 0);
            acc1b = __builtin_amdgcn_mfma_f32_32x32x16_f16(ah, cl1, acc1b, 0, 0, 0);
        }
    }
    __syncthreads();  // all x reads done; region A becomes h1 planes

    // BN + ReLU epilogue; write h1 hi/lo planes (stride 264).
    {
#pragma unroll
        for (int nt = 0; nt < 2; ++nt) {
            int j = w * 64 + nt * 32 + ln31;
            float sc = gm[j] * rsqrtf(vr[j] + EPS_BN);
            float sh = (b1[j] - mu[j]) * sc + bt[j];
            const f32x16& a = nt ? acc1b : acc1a;
#pragma unroll
            for (int r = 0; r < 16; ++r) {
                int row = (r & 3) + 8 * (r >> 2) + 4 * q;
                float v = a[r] * sc + sh;
                v = v > 0.f ? v : 0.f;
                f16 h = (f16)v;
                sm[row * 264 + j]        = h;
                sm[8448 + row * 264 + j] = (f16)(v - (float)h);
            }
        }
    }
    __syncthreads();  // h1 ready

    // ================= Stage 2: h2 = ReLU(h1 @ W2^T + b2) ===================
    f32x16 acc2a = {};
    f32x16 acc2b = {};
    {
        const f16* q2h = p2h + (size_t)w * 512 + lane * 8;
        const f16* q2l = p2l + (size_t)w * 512 + lane * 8;
        f16x8 bh = *(const f16x8*)(q2h);
        f16x8 bl = *(const f16x8*)(q2l);
#pragma unroll 2
        for (int kst = 0; kst < 16; ++kst) {
            f16x8 cbh = bh, cbl = bl;
            int kn = (kst + 1) & 15;
            bh = *(const f16x8*)(q2h + (size_t)kn * 2048);
            bl = *(const f16x8*)(q2l + (size_t)kn * 2048);
            int koff = kst * 16 + q * 8;
            f16x8 ah = *(const f16x8*)(sm + ln31 * 264 + koff);
            f16x8 al = *(const f16x8*)(sm + 8448 + ln31 * 264 + koff);
            f32x16& acc = (kst & 1) ? acc2b : acc2a;
            acc = __builtin_amdgcn_mfma_f32_32x32x16_f16(ah, cbh, acc, 0, 0, 0);
            acc = __builtin_amdgcn_mfma_f32_32x32x16_f16(al, cbh, acc, 0, 0, 0);
            acc = __builtin_amdgcn_mfma_f32_32x32x16_f16(ah, cbl, acc, 0, 0, 0);
        }
    }
    // ReLU epilogue -> h2 planes in region B.
    {
        int j2 = w * 32 + ln31;
        float bias = b2[j2];
#pragma unroll
        for (int r = 0; r < 16; ++r) {
            int row = (r & 3) + 8 * (r >> 2) + 4 * q;
            float v = (acc2a[r] + acc2b[r]) + bias;
            v = v > 0.f ? v : 0.f;
            f16 h = (f16)v;
            sm[16896 + row * 136 + j2] = h;
            sm[21248 + row * 136 + j2] = (f16)(v - (float)h);
        }
    }
    __syncthreads();  // h2 ready

    // ================= Stage 3: z = tanh(h2 @ W3^T + b3) ====================
    if (w < 2) {  // 64 output cols -> waves 0,1 only
        f32x16 acc3a = {};
        f32x16 acc3b = {};
        const f16* q3h = p3h + (size_t)w * 512 + lane * 8;
        const f16* q3l = p3l + (size_t)w * 512 + lane * 8;
        f16x8 bh = *(const f16x8*)(q3h);
        f16x8 bl = *(const f16x8*)(q3l);
#pragma unroll 2
        for (int ks = 0; ks < 8; ++ks) {
            f16x8 cbh = bh, cbl = bl;
            int kn = (ks + 1) & 7;
            bh = *(const f16x8*)(q3h + (size_t)kn * 1024);
            bl = *(const f16x8*)(q3l + (size_t)kn * 1024);
            f16x8 ah = *(const f16x8*)(sm + 16896 + ln31 * 136 + ks * 16 + q * 8);
            f16x8 al = *(const f16x8*)(sm + 21248 + ln31 * 136 + ks * 16 + q * 8);
            f32x16& acc = (ks & 1) ? acc3b : acc3a;
            acc = __builtin_amdgcn_mfma_f32_32x32x16_f16(ah, cbh, acc, 0, 0, 0);
            acc = __builtin_amdgcn_mfma_f32_32x32x16_f16(al, cbh, acc, 0, 0, 0);
            acc = __builtin_amdgcn_mfma_f32_32x32x16_f16(ah, cbl, acc, 0, 0, 0);
        }
        int j3 = w * 32 + ln31;
        float bias = b3[j3];
#pragma unroll
        for (int r = 0; r < 16; ++r) {
            int row = (r & 3) + 8 * (r >> 2) + 4 * q;
            float zv = tanhf((acc3a[r] + acc3b[r]) + bias);
            f16 h = (f16)zv;
            size_t idx = (size_t)(r0 + row) * EMB_DIM + j3;
            Zh[idx] = h;
            Zl[idx] = (f16)(zv - (float)h);
        }
    }
}

// ---------------------------------------------------------------------------
// Kernel 2: MFMA argmin. 128 rows/block, 256 threads (4 waves), grid 512.
// Wave w owns row-tile w (rows r0+w*32..+31) and consumes ALL 4 ct from the
// shared LDS chunk. Double-buffered DMA staging via global_load_lds:
//   iter ch: stage(ch+1 -> buf^1) issued FIRST (lands under compute);
//            compute(buf) = 4 ct x {8 b128 LDS reads, 12 MFMA, 16-cell cmp};
//            __syncthreads() (drains vmcnt -> next buf ready, this buf free).
// LDS 2 x 32KB = 64KB -> 2 blocks/CU. Codebook L2 traffic 4x lower than R9.
// score(r,c) = z_r.e_c - 0.5||e_c||^2, maximized == argmin distance.
// Visit order (ch asc, ct asc) and per-cell math identical -> absmax 0.
// No ct-merge needed (one wave per row); only 32-lane column reduction.
// ---------------------------------------------------------------------------
__global__ __launch_bounds__(256) void k_argmin_mfma(
    const f16* __restrict__ Zh, const f16* __restrict__ Zl,
    const f16* __restrict__ cfh, const f16* __restrict__ cfl,
    const float* __restrict__ norms, int* __restrict__ out) {
    __shared__ __align__(16) f16 sm[32768];  // 64KB: buf b at b*16384 (H), +8192 (L)
    const int tid  = threadIdx.x;
    const int lane = tid & 63;
    const int w    = tid >> 6;      // 0..3 = row-tile
    const int ln31 = lane & 31;
    const int q    = lane >> 5;
    const int r0   = blockIdx.x * 128;

    // z fragments: 8 x 16B per lane, straight from global (row-major Z).
    f16x8 ah[4], al[4];
#pragma unroll
    for (int ks = 0; ks < 4; ++ks) {
        size_t zoff = (size_t)(r0 + w * 32 + ln31) * EMB_DIM + ks * 16 + q * 8;
        ah[ks] = *(const f16x8*)(Zh + zoff);
        al[ks] = *(const f16x8*)(Zl + zoff);
    }

    float bv[16];
    int   bi[16];
#pragma unroll
    for (int i = 0; i < 16; ++i) { bv[i] = -3.4e38f; bi[i] = 0; }

    // DMA one 32KB chunk (16KB hi + 16KB lo) into buffer b.
    // Per thread: 8 x global_load_lds width-16; lane-linear dest (wave-uniform
    // base + lane*16) matches the required contiguous pattern.
#define STAGE(CH, B) do {                                                     \
        const f16* sH_ = cfh + (size_t)(CH) * 8192;                           \
        const f16* sL_ = cfl + (size_t)(CH) * 8192;                           \
        f16* dH_ = sm + (B) * 16384;                                          \
        f16* dL_ = sm + (B) * 16384 + 8192;                                   \
        _Pragma("unroll")                                                     \
        for (int it_ = 0; it_ < 4; ++it_) {                                   \
            int off_ = (it_ * 256 + tid) * 8;                                 \
            __builtin_amdgcn_global_load_lds(                                 \
                (const __attribute__((address_space(1))) void*)(sH_ + off_),  \
                (__attribute__((address_space(3))) void*)(dH_ + off_),        \
                16, 0, 0);                                                    \
            __builtin_amdgcn_global_load_lds(                                 \
                (const __attribute__((address_space(1))) void*)(sL_ + off_),  \
                (__attribute__((address_space(3))) void*)(dL_ + off_),        \
                16, 0, 0);                                                    \
        }                                                                     \
    } while (0)

    STAGE(0, 0);
    __syncthreads();   // prologue: buf0 ready (barrier drains vmcnt)

#pragma unroll 1
    for (int ch = 0; ch < 32; ++ch) {
        int b = ch & 1;
        if (ch + 1 < 32) STAGE(ch + 1, b ^ 1);   // DMA lands under compute
        const f16* ebh = sm + b * 16384;
        const f16* ebl = sm + b * 16384 + 8192;
#pragma unroll 2
        for (int ct = 0; ct < 4; ++ct) {
            f16x8 bh[4], bl[4];
#pragma unroll
            for (int ks = 0; ks < 4; ++ks) {
                int off = (ks * 4 + ct) * 512 + lane * 8;
                bh[ks] = *(const f16x8*)(ebh + off);
                bl[ks] = *(const f16x8*)(ebl + off);
            }
            f32x16 acc0 = {};
            f32x16 acc1 = {};
#pragma unroll
            for (int ks = 0; ks < 4; ks += 2) {
                acc0 = __builtin_amdgcn_mfma_f32_32x32x16_f16(ah[ks],     bh[ks],     acc0, 0, 0, 0);
                acc1 = __builtin_amdgcn_mfma_f32_32x32x16_f16(ah[ks + 1], bh[ks + 1], acc1, 0, 0, 0);
                acc0 = __builtin_amdgcn_mfma_f32_32x32x16_f16(al[ks],     bh[ks],     acc0, 0, 0, 0);
                acc1 = __builtin_amdgcn_mfma_f32_32x32x16_f16(al[ks + 1], bh[ks + 1], acc1, 0, 0, 0);
                acc0 = __builtin_amdgcn_mfma_f32_32x32x16_f16(ah[ks],     bl[ks],     acc0, 0, 0, 0);
                acc1 = __builtin_amdgcn_mfma_f32_32x32x16_f16(ah[ks + 1], bl[ks + 1], acc1, 0, 0, 0);
            }
            int   col = ch * 128 + ct * 32 + ln31;
            float nv  = norms[col];
#pragma unroll
            for (int r = 0; r < 16; ++r) {
                float t  = (acc0[r] + acc1[r]) - nv;
                bool  gt = t > bv[r];
                bv[r] = gt ? t : bv[r];
                bi[r] = gt ? col : bi[r];
            }
        }
        __syncthreads();  // drains vmcnt: buf^1 ready, buf free for re-stage
    }
#undef STAGE

    // ---- cross-lane reduction over 32 code-columns ------------------------
    float* redv = (float*)sm;                // [128][33] f32, bytes [0,16896)
    int*   redi = (int*)sm + 4224;           // [128][33] i32, bytes [16896,33792)
#pragma unroll
    for (int r = 0; r < 16; ++r) {
        int row = w * 32 + (r & 3) + 8 * (r >> 2) + 4 * q;
        redv[row * 33 + ln31] = bv[r];
        redi[row * 33 + ln31] = bi[r];
    }
    __syncthreads();
    if (tid < 128) {
        float v  = redv[tid * 33];
        int   ix = redi[tid * 33];
#pragma unroll
        for (int j = 1; j < 32; ++j) {
            float vj = redv[tid * 33 + j];
            int   ij = redi[tid * 33 + j];
            if (vj > v || (vj == v && ij < ix)) { v = vj; ix = ij; }
        }
        out[r0 + tid] = ix;
    }
}

// ---------------------------------------------------------------------------
extern "C" void kernel_launch(void* const* d_in, const int* in_sizes, int n_in,
                              void* d_out, int out_size, void* d_ws, size_t ws_size,
                              hipStream_t stream) {
    (void)n_in; (void)out_size; (void)ws_size;
    const float* x  = (const float*)d_in[0];
    const float* W1 = (const float*)d_in[1];
    const float* b1 = (const float*)d_in[2];
    const float* gm = (const float*)d_in[3];
    const float* bt = (const float*)d_in[4];
    const float* mu = (const float*)d_in[5];
    const float* vr = (const float*)d_in[6];
    const float* W2 = (const float*)d_in[7];
    const float* b2 = (const float*)d_in[8];
    const float* W3 = (const float*)d_in[9];
    const float* b3 = (const float*)d_in[10];
    const float* cb = (const float*)d_in[11];

    // Workspace layout (~17.4 MB) — same offsets as R6/R7
    char* ws = (char*)d_ws;
    float* norms = (float*)ws;                    // 16 KB
    f16* cfh = (f16*)(ws + 16384);                // 512 KB (cb frags hi)
    f16* cfl = (f16*)(ws + 540672);               // 512 KB (cb frags lo)
    f16* p1h = (f16*)(ws + 1064960);              // 128 KB
    f16* p1l = (f16*)(ws + 1196032);              // 128 KB
    f16* p2h = (f16*)(ws + 1327104);              // 64 KB
    f16* p2l = (f16*)(ws + 1392640);              // 64 KB
    f16* p3h = (f16*)(ws + 1458176);              // 16 KB
    f16* p3l = (f16*)(ws + 1474560);              // 16 KB
    f16* Zh  = (f16*)(ws + 1490944);              // 8 MB
    f16* Zl  = (f16*)(ws + 9879552);              // 8 MB
    int* out = (int*)d_out;

    const int B = in_sizes[0] / IN_DIM;  // 65536

    k_norms<<<K_CODES / 256, 256, 0, stream>>>(cb, norms);
    k_prep<<<180, 256, 0, stream>>>(W1, W2, W3, cb, p1h, p1l, p2h, p2l,
                                    p3h, p3l, cfh, cfl);
    k_encoder_mfma<<<B / 32, 256, 0, stream>>>(x, p1h, p1l, p2h, p2l, p3h, p3l,
                                               b1, gm, bt, mu, vr, b2, b3, Zh, Zl);
    k_argmin_mfma<<<B / 128, 256, 0, stream>>>(Zh, Zl, cfh, cfl, norms, out);
}

// Round 8
// 277.026 us; speedup vs baseline: 1.3912x; 1.0165x over previous
//
#include <hip/hip_runtime.h>

// Problem constants (fixed by reference)
#define IN_DIM  256
#define HID_DIM 256
#define H2_DIM  128
#define EMB_DIM 64
#define K_CODES 4096
#define EPS_BN  1e-5f

// R5: argmin on matrix pipe via fp16 hi/lo split (3 passes) -> 205us.
// R6: fused encoder. R7: fragment-major packing. R8: 8-wave lockstep
// staging (occupancy theory refuted for THAT structure; ct-merge proven
// exact). R9: barrier-free L2 streaming, 126us (latency-bound at 4 w/SIMD).
// R10: reg double-buffer REGRESSED (waitcnt serialization). R11: 2 row-
// tiles/wave REGRESSED (VGPR 136 -> occupancy 11.5%). R12: grid 1024
// REGRESSED (VGPR+AGPR caps waves; TLP flat). R13: global_load_lds DMA +
// double-buffer + wave-owns-row-tile: 119us, bank conflicts 0 — but
// OccupancyPercent 19.3%: 64KB LDS + 4-wave block = 2 waves/SIMD; MfmaUtil
// 40 + VALUBusy 57 = issue port saturated per wave-pair, chains exposed.
// R14: SAME DMA+dbuf body, 8 waves/block (512thr, 128 rows), grid 512:
// shared chunk feeds 8 waves -> 2 blocks/CU x 8 = 4 waves/SIMD (VGPR 108
// caps exactly 4). Waves split ct (hp = w>>2, 2 ct each); R8's exact
// ct-merge (lowest-index tie-break) + stride-17 publish (no conflicts).
// Per-cell MFMA order and score values bit-identical -> absmax 0.

typedef _Float16 f16;
typedef _Float16 f16x4 __attribute__((ext_vector_type(4)));
typedef _Float16 f16x8 __attribute__((ext_vector_type(8)));
typedef float    f32x16 __attribute__((ext_vector_type(16)));

// ---------------------------------------------------------------------------
// Kernel 0a: half squared norms of codebook rows: norms[c] = 0.5*||e_c||^2
// ---------------------------------------------------------------------------
__global__ __launch_bounds__(256) void k_norms(const float* __restrict__ cb,
                                               float* __restrict__ norms) {
    int c = blockIdx.x * 256 + threadIdx.x;
    const float4* row = reinterpret_cast<const float4*>(cb + (size_t)c * EMB_DIM);
    float s = 0.f;
#pragma unroll
    for (int i = 0; i < EMB_DIM / 4; ++i) {
        float4 v = row[i];
        s += v.x * v.x + v.y * v.y + v.z * v.z + v.w * v.w;
    }
    norms[c] = 0.5f * s;
}

// ---------------------------------------------------------------------------
// Kernel 0b: fragment-major hi/lo packer.
// A fragment = 512 f16 = what one wave loads for one (k16-step, 32-col-tile):
//   P[f*512 + l*8 + j] = W[ct*32 + (l&31)][k0 + (l>>5)*8 + j]
// f16x8 unit index t (one thread each), 46080 total:
//   [0,8192)      W1 [256][256]: f = kst*8 + ct   (kst<16, ct<8)
//   [8192,12288)  W2 [128][256]: f = kst*4 + ct   (kst<16, ct<4)
//   [12288,13312) W3 [ 64][128]: f = ks*2  + ct   (ks<8, ct<2)
//   [13312,46080) cb [4096][64]: f = (ch*4+ks)*4+ct (ch<32, ks<4, ct<4)
// ---------------------------------------------------------------------------
__global__ __launch_bounds__(256) void k_prep(
    const float* __restrict__ W1, const float* __restrict__ W2,
    const float* __restrict__ W3, const float* __restrict__ cb,
    f16* __restrict__ p1h, f16* __restrict__ p1l,
    f16* __restrict__ p2h, f16* __restrict__ p2l,
    f16* __restrict__ p3h, f16* __restrict__ p3l,
    f16* __restrict__ cfh, f16* __restrict__ cfl) {
    int t = blockIdx.x * 256 + threadIdx.x;   // < 46080
    const float* src; f16 *dh, *dl; int tt, row, k0, K;
    if (t < 8192) {
        tt = t; int f = tt >> 6, l = tt & 63;
        int ct = f & 7, kst = f >> 3;
        row = ct * 32 + (l & 31); k0 = kst * 16 + (l >> 5) * 8;
        src = W1; K = IN_DIM; dh = p1h; dl = p1l;
    } else if (t < 12288) {
        tt = t - 8192; int f = tt >> 6, l = tt & 63;
        int ct = f & 3, kst = f >> 2;
        row = ct * 32 + (l & 31); k0 = kst * 16 + (l >> 5) * 8;
        src = W2; K = HID_DIM; dh = p2h; dl = p2l;
    } else if (t < 13312) {
        tt = t - 12288; int f = tt >> 6, l = tt & 63;
        int ct = f & 1, ks = f >> 1;
        row = ct * 32 + (l & 31); k0 = ks * 16 + (l >> 5) * 8;
        src = W3; K = H2_DIM; dh = p3h; dl = p3l;
    } else {
        tt = t - 13312; int f = tt >> 6, l = tt & 63;
        int ct = f & 3, ks = (f >> 2) & 3, ch = f >> 4;
        row = ch * 128 + ct * 32 + (l & 31); k0 = ks * 16 + (l >> 5) * 8;
        src = cb; K = EMB_DIM; dh = cfh; dl = cfl;
    }
    const float* s = src + (size_t)row * K + k0;
    f16x8 hv, lv;
#pragma unroll
    for (int j = 0; j < 8; ++j) {
        float v = s[j];
        f16 h = (f16)v;
        hv[j] = h;
        lv[j] = (f16)(v - (float)h);
    }
    *(f16x8*)(dh + (size_t)tt * 8) = hv;
    *(f16x8*)(dl + (size_t)tt * 8) = lv;
}

// ---------------------------------------------------------------------------
// Kernel 1: fused MFMA encoder. 32 rows/block, 256 threads (4 waves).
// All GEMMs as v_mfma_f32_32x32x16_f16, 3 passes (hh, lh, hl) per k-step.
// A-frags from LDS (stride 264/136 f16); B-frags streamed from fragment-major
// global with 1-deep register prefetch. LDS 51.2 KB -> 3 blocks/CU. 4 barriers.
// (Unchanged this round for clean attribution of the argmin change.)
// ---------------------------------------------------------------------------
__global__ __launch_bounds__(256) void k_encoder_mfma(
    const float* __restrict__ x,
    const f16* __restrict__ p1h, const f16* __restrict__ p1l,
    const f16* __restrict__ p2h, const f16* __restrict__ p2l,
    const f16* __restrict__ p3h, const f16* __restrict__ p3l,
    const float* __restrict__ b1,
    const float* __restrict__ gm, const float* __restrict__ bt,
    const float* __restrict__ mu, const float* __restrict__ vr,
    const float* __restrict__ b2, const float* __restrict__ b3,
    f16* __restrict__ Zh, f16* __restrict__ Zl) {
    __shared__ __align__(16) f16 sm[25600];
    const int tid  = threadIdx.x;
    const int lane = tid & 63;
    const int w    = tid >> 6;
    const int ln31 = lane & 31;
    const int q    = lane >> 5;
    const int r0   = blockIdx.x * 32;

    // ---- stage x [32 rows][256 k] fp32 -> hi/lo f16 planes, once ----------
#pragma unroll
    for (int it = 0; it < 8; ++it) {
        int i = it * 256 + tid;              // float4 id, 2048 total
        int row = i >> 6, c4 = (i & 63) * 4;
        float4 v = *reinterpret_cast<const float4*>(
            x + (size_t)(r0 + row) * IN_DIM + c4);
        f16x4 hv, lv;
        hv[0] = (f16)v.x; lv[0] = (f16)(v.x - (float)hv[0]);
        hv[1] = (f16)v.y; lv[1] = (f16)(v.y - (float)hv[1]);
        hv[2] = (f16)v.z; lv[2] = (f16)(v.z - (float)hv[2]);
        hv[3] = (f16)v.w; lv[3] = (f16)(v.w - (float)hv[3]);
        *(f16x4*)(sm + row * 264 + c4)        = hv;
        *(f16x4*)(sm + 8448 + row * 264 + c4) = lv;
    }
    __syncthreads();

    // ================= Stage 1: h1 = BN+ReLU(x @ W1^T) ======================
    f32x16 acc1a = {};
    f32x16 acc1b = {};
    {
        const f16* q1h = p1h + (size_t)(2 * w) * 512 + lane * 8;
        const f16* q1l = p1l + (size_t)(2 * w) * 512 + lane * 8;
        f16x8 bh0 = *(const f16x8*)(q1h);
        f16x8 bh1 = *(const f16x8*)(q1h + 512);
        f16x8 bl0 = *(const f16x8*)(q1l);
        f16x8 bl1 = *(const f16x8*)(q1l + 512);
#pragma unroll 2
        for (int kst = 0; kst < 16; ++kst) {
            f16x8 ch0 = bh0, ch1 = bh1, cl0 = bl0, cl1 = bl1;
            int kn = (kst + 1) & 15;  // wrap: last prefetch redundant, harmless
            bh0 = *(const f16x8*)(q1h + (size_t)kn * 4096);
            bh1 = *(const f16x8*)(q1h + (size_t)kn * 4096 + 512);
            bl0 = *(const f16x8*)(q1l + (size_t)kn * 4096);
            bl1 = *(const f16x8*)(q1l + (size_t)kn * 4096 + 512);
            int koff = kst * 16 + q * 8;
            f16x8 ah = *(const f16x8*)(sm + ln31 * 264 + koff);
            f16x8 al = *(const f16x8*)(sm + 8448 + ln31 * 264 + koff);
            acc1a = __builtin_amdgcn_mfma_f32_32x32x16_f16(ah, ch0, acc1a, 0, 0, 0);
            acc1b = __builtin_amdgcn_mfma_f32_32x32x16_f16(ah, ch1, acc1b, 0, 0, 0);
            acc1a = __builtin_amdgcn_mfma_f32_32x32x16_f16(al, ch0, acc1a, 0, 0, 0);
            acc1b = __builtin_amdgcn_mfma_f32_32x32x16_f16(al, ch1, acc1b, 0, 0, 0);
            acc1a = __builtin_amdgcn_mfma_f32_32x32x16_f16(ah, cl0, acc1a, 0, 0, 0);
            acc1b = __builtin_amdgcn_mfma_f32_32x32x16_f16(ah, cl1, acc1b, 0, 0, 0);
        }
    }
    __syncthreads();  // all x reads done; region A becomes h1 planes

    // BN + ReLU epilogue; write h1 hi/lo planes (stride 264).
    {
#pragma unroll
        for (int nt = 0; nt < 2; ++nt) {
            int j = w * 64 + nt * 32 + ln31;
            float sc = gm[j] * rsqrtf(vr[j] + EPS_BN);
            float sh = (b1[j] - mu[j]) * sc + bt[j];
            const f32x16& a = nt ? acc1b : acc1a;
#pragma unroll
            for (int r = 0; r < 16; ++r) {
                int row = (r & 3) + 8 * (r >> 2) + 4 * q;
                float v = a[r] * sc + sh;
                v = v > 0.f ? v : 0.f;
                f16 h = (f16)v;
                sm[row * 264 + j]        = h;
                sm[8448 + row * 264 + j] = (f16)(v - (float)h);
            }
        }
    }
    __syncthreads();  // h1 ready

    // ================= Stage 2: h2 = ReLU(h1 @ W2^T + b2) ===================
    f32x16 acc2a = {};
    f32x16 acc2b = {};
    {
        const f16* q2h = p2h + (size_t)w * 512 + lane * 8;
        const f16* q2l = p2l + (size_t)w * 512 + lane * 8;
        f16x8 bh = *(const f16x8*)(q2h);
        f16x8 bl = *(const f16x8*)(q2l);
#pragma unroll 2
        for (int kst = 0; kst < 16; ++kst) {
            f16x8 cbh = bh, cbl = bl;
            int kn = (kst + 1) & 15;
            bh = *(const f16x8*)(q2h + (size_t)kn * 2048);
            bl = *(const f16x8*)(q2l + (size_t)kn * 2048);
            int koff = kst * 16 + q * 8;
            f16x8 ah = *(const f16x8*)(sm + ln31 * 264 + koff);
            f16x8 al = *(const f16x8*)(sm + 8448 + ln31 * 264 + koff);
            f32x16& acc = (kst & 1) ? acc2b : acc2a;
            acc = __builtin_amdgcn_mfma_f32_32x32x16_f16(ah, cbh, acc, 0, 0, 0);
            acc = __builtin_amdgcn_mfma_f32_32x32x16_f16(al, cbh, acc, 0, 0, 0);
            acc = __builtin_amdgcn_mfma_f32_32x32x16_f16(ah, cbl, acc, 0, 0, 0);
        }
    }
    // ReLU epilogue -> h2 planes in region B.
    {
        int j2 = w * 32 + ln31;
        float bias = b2[j2];
#pragma unroll
        for (int r = 0; r < 16; ++r) {
            int row = (r & 3) + 8 * (r >> 2) + 4 * q;
            float v = (acc2a[r] + acc2b[r]) + bias;
            v = v > 0.f ? v : 0.f;
            f16 h = (f16)v;
            sm[16896 + row * 136 + j2] = h;
            sm[21248 + row * 136 + j2] = (f16)(v - (float)h);
        }
    }
    __syncthreads();  // h2 ready

    // ================= Stage 3: z = tanh(h2 @ W3^T + b3) ====================
    if (w < 2) {  // 64 output cols -> waves 0,1 only
        f32x16 acc3a = {};
        f32x16 acc3b = {};
        const f16* q3h = p3h + (size_t)w * 512 + lane * 8;
        const f16* q3l = p3l + (size_t)w * 512 + lane * 8;
        f16x8 bh = *(const f16x8*)(q3h);
        f16x8 bl = *(const f16x8*)(q3l);
#pragma unroll 2
        for (int ks = 0; ks < 8; ++ks) {
            f16x8 cbh = bh, cbl = bl;
            int kn = (ks + 1) & 7;
            bh = *(const f16x8*)(q3h + (size_t)kn * 1024);
            bl = *(const f16x8*)(q3l + (size_t)kn * 1024);
            f16x8 ah = *(const f16x8*)(sm + 16896 + ln31 * 136 + ks * 16 + q * 8);
            f16x8 al = *(const f16x8*)(sm + 21248 + ln31 * 136 + ks * 16 + q * 8);
            f32x16& acc = (ks & 1) ? acc3b : acc3a;
            acc = __builtin_amdgcn_mfma_f32_32x32x16_f16(ah, cbh, acc, 0, 0, 0);
            acc = __builtin_amdgcn_mfma_f32_32x32x16_f16(al, cbh, acc, 0, 0, 0);
            acc = __builtin_amdgcn_mfma_f32_32x32x16_f16(ah, cbl, acc, 0, 0, 0);
        }
        int j3 = w * 32 + ln31;
        float bias = b3[j3];
#pragma unroll
        for (int r = 0; r < 16; ++r) {
            int row = (r & 3) + 8 * (r >> 2) + 4 * q;
            float zv = tanhf((acc3a[r] + acc3b[r]) + bias);
            f16 h = (f16)zv;
            size_t idx = (size_t)(r0 + row) * EMB_DIM + j3;
            Zh[idx] = h;
            Zl[idx] = (f16)(zv - (float)h);
        }
    }
}

// ---------------------------------------------------------------------------
// Kernel 2: MFMA argmin. 128 rows/block, 512 threads (8 waves), grid 512.
// Wave w: rt = w&3 (row-tile), hp = w>>2 (ct-half: cts {2hp, 2hp+1}).
// Double-buffered global_load_lds DMA staging (R13); the shared 32KB chunk
// now feeds 8 waves -> 2 blocks/CU x 8 waves = 16 waves/CU = 4 waves/SIMD
// (VGPR ~108 caps exactly 4). Per wave-ch: 2 ct x {8 b128 reads, 12 MFMA,
// 16-cell cmp}. score(r,c) = z_r.e_c - 0.5||e_c||^2, maximized == argmin.
// Values + per-ct MFMA order bit-identical; ct-split merge with lowest-
// index tie-break == sequential first-occurrence argmin (R8) -> absmax 0.
// Publish buffers stride-17 padded -> conflict-free.
// ---------------------------------------------------------------------------
__global__ __launch_bounds__(512) void k_argmin_mfma(
    const f16* __restrict__ Zh, const f16* __restrict__ Zl,
    const f16* __restrict__ cfh, const f16* __restrict__ cfl,
    const float* __restrict__ norms, int* __restrict__ out) {
    __shared__ __align__(16) f16 sm[32768];  // 64KB: buf b at b*16384 (H), +8192 (L)
    const int tid  = threadIdx.x;
    const int lane = tid & 63;
    const int w    = tid >> 6;      // 0..7
    const int rt   = w & 3;         // row-tile
    const int hp   = w >> 2;        // ct-half (0,1)
    const int ln31 = lane & 31;
    const int q    = lane >> 5;
    const int r0   = blockIdx.x * 128;

    // z fragments: 8 x 16B per lane, straight from global (row-major Z).
    // hp=0/1 wave pairs share rows (duplicate read, L2-served).
    f16x8 ah[4], al[4];
#pragma unroll
    for (int ks = 0; ks < 4; ++ks) {
        size_t zoff = (size_t)(r0 + rt * 32 + ln31) * EMB_DIM + ks * 16 + q * 8;
        ah[ks] = *(const f16x8*)(Zh + zoff);
        al[ks] = *(const f16x8*)(Zl + zoff);
    }

    float bv[16];
    int   bi[16];
#pragma unroll
    for (int i = 0; i < 16; ++i) { bv[i] = -3.4e38f; bi[i] = 0; }

    // DMA one 32KB chunk (16KB hi + 16KB lo) into buffer b. 512 threads ->
    // 4 loads/thread. Lane-linear dest matches the contiguous requirement.
#define STAGE(CH, B) do {                                                     \
        const f16* sH_ = cfh + (size_t)(CH) * 8192;                           \
        const f16* sL_ = cfl + (size_t)(CH) * 8192;                           \
        f16* dH_ = sm + (B) * 16384;                                          \
        f16* dL_ = sm + (B) * 16384 + 8192;                                   \
        _Pragma("unroll")                                                     \
        for (int it_ = 0; it_ < 2; ++it_) {                                   \
            int off_ = (it_ * 512 + tid) * 8;                                 \
            __builtin_amdgcn_global_load_lds(                                 \
                (const __attribute__((address_space(1))) void*)(sH_ + off_),  \
                (__attribute__((address_space(3))) void*)(dH_ + off_),        \
                16, 0, 0);                                                    \
            __builtin_amdgcn_global_load_lds(                                 \
                (const __attribute__((address_space(1))) void*)(sL_ + off_),  \
                (__attribute__((address_space(3))) void*)(dL_ + off_),        \
                16, 0, 0);                                                    \
        }                                                                     \
    } while (0)

    STAGE(0, 0);
    __syncthreads();   // prologue: buf0 ready (barrier drains vmcnt)

#pragma unroll 1
    for (int ch = 0; ch < 32; ++ch) {
        int b = ch & 1;
        if (ch + 1 < 32) STAGE(ch + 1, b ^ 1);   // DMA lands under compute
        const f16* ebh = sm + b * 16384;
        const f16* ebl = sm + b * 16384 + 8192;
#pragma unroll
        for (int c2 = 0; c2 < 2; ++c2) {
            int ct = hp * 2 + c2;
            f16x8 bh[4], bl[4];
#pragma unroll
            for (int ks = 0; ks < 4; ++ks) {
                int off = (ks * 4 + ct) * 512 + lane * 8;
                bh[ks] = *(const f16x8*)(ebh + off);
                bl[ks] = *(const f16x8*)(ebl + off);
            }
            f32x16 acc0 = {};
            f32x16 acc1 = {};
#pragma unroll
            for (int ks = 0; ks < 4; ks += 2) {
                acc0 = __builtin_amdgcn_mfma_f32_32x32x16_f16(ah[ks],     bh[ks],     acc0, 0, 0, 0);
                acc1 = __builtin_amdgcn_mfma_f32_32x32x16_f16(ah[ks + 1], bh[ks + 1], acc1, 0, 0, 0);
                acc0 = __builtin_amdgcn_mfma_f32_32x32x16_f16(al[ks],     bh[ks],     acc0, 0, 0, 0);
                acc1 = __builtin_amdgcn_mfma_f32_32x32x16_f16(al[ks + 1], bh[ks + 1], acc1, 0, 0, 0);
                acc0 = __builtin_amdgcn_mfma_f32_32x32x16_f16(ah[ks],     bl[ks],     acc0, 0, 0, 0);
                acc1 = __builtin_amdgcn_mfma_f32_32x32x16_f16(ah[ks + 1], bl[ks + 1], acc1, 0, 0, 0);
            }
            int   col = ch * 128 + ct * 32 + ln31;
            float nv  = norms[col];
#pragma unroll
            for (int r = 0; r < 16; ++r) {
                float t  = (acc0[r] + acc1[r]) - nv;
                bool  gt = t > bv[r];
                bv[r] = gt ? t : bv[r];
                bi[r] = gt ? col : bi[r];
            }
        }
        __syncthreads();  // drains vmcnt: buf^1 ready, buf free for re-stage
    }
#undef STAGE

    // ---- merge ct-halves: hp=1 waves publish, hp=0 partners combine -------
    // pv [4][64][17] f32 (stride-17 pad, conflict-free), pi after: 34.8KB.
    {
        float* pv = (float*)sm;
        int*   pi = (int*)sm + 4352;
        if (hp == 1) {
#pragma unroll
            for (int r = 0; r < 16; ++r) {
                pv[rt * 1088 + lane * 17 + r] = bv[r];
                pi[rt * 1088 + lane * 17 + r] = bi[r];
            }
        }
        __syncthreads();
        if (hp == 0) {
#pragma unroll
            for (int r = 0; r < 16; ++r) {
                float v2 = pv[rt * 1088 + lane * 17 + r];
                int   i2 = pi[rt * 1088 + lane * 17 + r];
                // lowest-index-on-tie == reference argmin (first occurrence)
                bool tk = (v2 > bv[r]) || (v2 == bv[r] && i2 < bi[r]);
                bv[r] = tk ? v2 : bv[r];
                bi[r] = tk ? i2 : bi[r];
            }
        }
    }
    __syncthreads();  // publish-buffer reads done before redv overwrites

    // ---- cross-lane reduction over 32 code-columns ------------------------
    float* redv = (float*)sm;                // [128][33] f32, bytes [0,16896)
    int*   redi = (int*)sm + 4224;           // [128][33] i32, bytes [16896,33792)
    if (hp == 0) {
#pragma unroll
        for (int r = 0; r < 16; ++r) {
            int row = rt * 32 + (r & 3) + 8 * (r >> 2) + 4 * q;
            redv[row * 33 + ln31] = bv[r];
            redi[row * 33 + ln31] = bi[r];
        }
    }
    __syncthreads();
    if (tid < 128) {
        float v  = redv[tid * 33];
        int   ix = redi[tid * 33];
#pragma unroll
        for (int j = 1; j < 32; ++j) {
            float vj = redv[tid * 33 + j];
            int   ij = redi[tid * 33 + j];
            if (vj > v || (vj == v && ij < ix)) { v = vj; ix = ij; }
        }
        out[r0 + tid] = ix;
    }
}

// ---------------------------------------------------------------------------
extern "C" void kernel_launch(void* const* d_in, const int* in_sizes, int n_in,
                              void* d_out, int out_size, void* d_ws, size_t ws_size,
                              hipStream_t stream) {
    (void)n_in; (void)out_size; (void)ws_size;
    const float* x  = (const float*)d_in[0];
    const float* W1 = (const float*)d_in[1];
    const float* b1 = (const float*)d_in[2];
    const float* gm = (const float*)d_in[3];
    const float* bt = (const float*)d_in[4];
    const float* mu = (const float*)d_in[5];
    const float* vr = (const float*)d_in[6];
    const float* W2 = (const float*)d_in[7];
    const float* b2 = (const float*)d_in[8];
    const float* W3 = (const float*)d_in[9];
    const float* b3 = (const float*)d_in[10];
    const float* cb = (const float*)d_in[11];

    // Workspace layout (~17.4 MB) — same offsets as R6/R7
    char* ws = (char*)d_ws;
    float* norms = (float*)ws;                    // 16 KB
    f16* cfh = (f16*)(ws + 16384);                // 512 KB (cb frags hi)
    f16* cfl = (f16*)(ws + 540672);               // 512 KB (cb frags lo)
    f16* p1h = (f16*)(ws + 1064960);              // 128 KB
    f16* p1l = (f16*)(ws + 1196032);              // 128 KB
    f16* p2h = (f16*)(ws + 1327104);              // 64 KB
    f16* p2l = (f16*)(ws + 1392640);              // 64 KB
    f16* p3h = (f16*)(ws + 1458176);              // 16 KB
    f16* p3l = (f16*)(ws + 1474560);              // 16 KB
    f16* Zh  = (f16*)(ws + 1490944);              // 8 MB
    f16* Zl  = (f16*)(ws + 9879552);              // 8 MB
    int* out = (int*)d_out;

    const int B = in_sizes[0] / IN_DIM;  // 65536

    k_norms<<<K_CODES / 256, 256, 0, stream>>>(cb, norms);
    k_prep<<<180, 256, 0, stream>>>(W1, W2, W3, cb, p1h, p1l, p2h, p2l,
                                    p3h, p3l, cfh, cfl);
    k_encoder_mfma<<<B / 32, 256, 0, stream>>>(x, p1h, p1l, p2h, p2l, p3h, p3l,
                                               b1, gm, bt, mu, vr, b2, b3, Zh, Zl);
    k_argmin_mfma<<<B / 128, 512, 0, stream>>>(Zh, Zl, cfh, cfl, norms, out);
}

// Round 10
// 267.194 us; speedup vs baseline: 1.4424x; 1.0368x over previous
//
#include <hip/hip_runtime.h>

// Problem constants (fixed by reference)
#define IN_DIM  256
#define HID_DIM 256
#define H2_DIM  128
#define EMB_DIM 64
#define K_CODES 4096
#define EPS_BN  1e-5f

// History: R5 hi/lo-split MFMA argmin 205us. R6 fused encoder 295. R7 frag
// packing (null). R8 8-wave lockstep (null). R9 barrier-free stream 126.
// R10/R11/R12 REGRESS (waitcnt serialization / VGPR / grid shape). R13
// global_load_lds DMA + dbuf, 4 waves: 119us BEST. R14 8-wave share REGRESS.
// R15 FAILED absmax 1156: folding -nv into the MFMA C-init reorders score
// rounding by ~1ulp -> flips near-ties in the DISCRETE argmin. RULE: never
// reorder the score arithmetic; the exact R5/R13 accumulation order (acc
// from 0, subtract nv in fp32 after) is part of the verified contract.
// R16: argmin reverted to R13 VERBATIM; keep R15's encoder LDS aliasing
// (bit-identical: only LDS addresses changed; h2 planes reuse region A
// after an added barrier) -> encoder LDS 51.2 -> 33KB -> 4 blocks/CU.

typedef _Float16 f16;
typedef _Float16 f16x4 __attribute__((ext_vector_type(4)));
typedef _Float16 f16x8 __attribute__((ext_vector_type(8)));
typedef float    f32x16 __attribute__((ext_vector_type(16)));

// ---------------------------------------------------------------------------
// Kernel 0a: half squared norms of codebook rows: norms[c] = 0.5*||e_c||^2
// ---------------------------------------------------------------------------
__global__ __launch_bounds__(256) void k_norms(const float* __restrict__ cb,
                                               float* __restrict__ norms) {
    int c = blockIdx.x * 256 + threadIdx.x;
    const float4* row = reinterpret_cast<const float4*>(cb + (size_t)c * EMB_DIM);
    float s = 0.f;
#pragma unroll
    for (int i = 0; i < EMB_DIM / 4; ++i) {
        float4 v = row[i];
        s += v.x * v.x + v.y * v.y + v.z * v.z + v.w * v.w;
    }
    norms[c] = 0.5f * s;
}

// ---------------------------------------------------------------------------
// Kernel 0b: fragment-major hi/lo packer.
// A fragment = 512 f16 = what one wave loads for one (k16-step, 32-col-tile):
//   P[f*512 + l*8 + j] = W[ct*32 + (l&31)][k0 + (l>>5)*8 + j]
// f16x8 unit index t (one thread each), 46080 total:
//   [0,8192)      W1 [256][256]: f = kst*8 + ct   (kst<16, ct<8)
//   [8192,12288)  W2 [128][256]: f = kst*4 + ct   (kst<16, ct<4)
//   [12288,13312) W3 [ 64][128]: f = ks*2  + ct   (ks<8, ct<2)
//   [13312,46080) cb [4096][64]: f = (ch*4+ks)*4+ct (ch<32, ks<4, ct<4)
// ---------------------------------------------------------------------------
__global__ __launch_bounds__(256) void k_prep(
    const float* __restrict__ W1, const float* __restrict__ W2,
    const float* __restrict__ W3, const float* __restrict__ cb,
    f16* __restrict__ p1h, f16* __restrict__ p1l,
    f16* __restrict__ p2h, f16* __restrict__ p2l,
    f16* __restrict__ p3h, f16* __restrict__ p3l,
    f16* __restrict__ cfh, f16* __restrict__ cfl) {
    int t = blockIdx.x * 256 + threadIdx.x;   // < 46080
    const float* src; f16 *dh, *dl; int tt, row, k0, K;
    if (t < 8192) {
        tt = t; int f = tt >> 6, l = tt & 63;
        int ct = f & 7, kst = f >> 3;
        row = ct * 32 + (l & 31); k0 = kst * 16 + (l >> 5) * 8;
        src = W1; K = IN_DIM; dh = p1h; dl = p1l;
    } else if (t < 12288) {
        tt = t - 8192; int f = tt >> 6, l = tt & 63;
        int ct = f & 3, kst = f >> 2;
        row = ct * 32 + (l & 31); k0 = kst * 16 + (l >> 5) * 8;
        src = W2; K = HID_DIM; dh = p2h; dl = p2l;
    } else if (t < 13312) {
        tt = t - 12288; int f = tt >> 6, l = tt & 63;
        int ct = f & 1, ks = f >> 1;
        row = ct * 32 + (l & 31); k0 = ks * 16 + (l >> 5) * 8;
        src = W3; K = H2_DIM; dh = p3h; dl = p3l;
    } else {
        tt = t - 13312; int f = tt >> 6, l = tt & 63;
        int ct = f & 3, ks = (f >> 2) & 3, ch = f >> 4;
        row = ch * 128 + ct * 32 + (l & 31); k0 = ks * 16 + (l >> 5) * 8;
        src = cb; K = EMB_DIM; dh = cfh; dl = cfl;
    }
    const float* s = src + (size_t)row * K + k0;
    f16x8 hv, lv;
#pragma unroll
    for (int j = 0; j < 8; ++j) {
        float v = s[j];
        f16 h = (f16)v;
        hv[j] = h;
        lv[j] = (f16)(v - (float)h);
    }
    *(f16x8*)(dh + (size_t)tt * 8) = hv;
    *(f16x8*)(dl + (size_t)tt * 8) = lv;
}

// ---------------------------------------------------------------------------
// Kernel 1: fused MFMA encoder. 32 rows/block, 256 threads (4 waves).
// All GEMMs as v_mfma_f32_32x32x16_f16, 3 passes (hh, lh, hl) per k-step.
// A-frags from LDS; B-frags streamed from fragment-major global with 1-deep
// register prefetch. h2 planes ALIASED into region A after stage-2 k-loop
// (extra barrier; bit-identical values) -> LDS 33KB -> 4 blocks/CU.
// LDS map: region A [0,16896) f16: xh/h1h@0, xl/h1l@8448 (stride 264);
//          after stage-2 k-loop: h2h@0, h2l@4352 (stride 136).
// ---------------------------------------------------------------------------
__global__ __launch_bounds__(256) void k_encoder_mfma(
    const float* __restrict__ x,
    const f16* __restrict__ p1h, const f16* __restrict__ p1l,
    const f16* __restrict__ p2h, const f16* __restrict__ p2l,
    const f16* __restrict__ p3h, const f16* __restrict__ p3l,
    const float* __restrict__ b1,
    const float* __restrict__ gm, const float* __restrict__ bt,
    const float* __restrict__ mu, const float* __restrict__ vr,
    const float* __restrict__ b2, const float* __restrict__ b3,
    f16* __restrict__ Zh, f16* __restrict__ Zl) {
    __shared__ __align__(16) f16 sm[16896];   // 33 KB -> 4 blocks/CU
    const int tid  = threadIdx.x;
    const int lane = tid & 63;
    const int w    = tid >> 6;
    const int ln31 = lane & 31;
    const int q    = lane >> 5;
    const int r0   = blockIdx.x * 32;

    // ---- stage x [32 rows][256 k] fp32 -> hi/lo f16 planes, once ----------
#pragma unroll
    for (int it = 0; it < 8; ++it) {
        int i = it * 256 + tid;              // float4 id, 2048 total
        int row = i >> 6, c4 = (i & 63) * 4;
        float4 v = *reinterpret_cast<const float4*>(
            x + (size_t)(r0 + row) * IN_DIM + c4);
        f16x4 hv, lv;
        hv[0] = (f16)v.x; lv[0] = (f16)(v.x - (float)hv[0]);
        hv[1] = (f16)v.y; lv[1] = (f16)(v.y - (float)hv[1]);
        hv[2] = (f16)v.z; lv[2] = (f16)(v.z - (float)hv[2]);
        hv[3] = (f16)v.w; lv[3] = (f16)(v.w - (float)hv[3]);
        *(f16x4*)(sm + row * 264 + c4)        = hv;
        *(f16x4*)(sm + 8448 + row * 264 + c4) = lv;
    }
    __syncthreads();

    // ================= Stage 1: h1 = BN+ReLU(x @ W1^T) ======================
    f32x16 acc1a = {};
    f32x16 acc1b = {};
    {
        const f16* q1h = p1h + (size_t)(2 * w) * 512 + lane * 8;
        const f16* q1l = p1l + (size_t)(2 * w) * 512 + lane * 8;
        f16x8 bh0 = *(const f16x8*)(q1h);
        f16x8 bh1 = *(const f16x8*)(q1h + 512);
        f16x8 bl0 = *(const f16x8*)(q1l);
        f16x8 bl1 = *(const f16x8*)(q1l + 512);
#pragma unroll 2
        for (int kst = 0; kst < 16; ++kst) {
            f16x8 ch0 = bh0, ch1 = bh1, cl0 = bl0, cl1 = bl1;
            int kn = (kst + 1) & 15;  // wrap: last prefetch redundant, harmless
            bh0 = *(const f16x8*)(q1h + (size_t)kn * 4096);
            bh1 = *(const f16x8*)(q1h + (size_t)kn * 4096 + 512);
            bl0 = *(const f16x8*)(q1l + (size_t)kn * 4096);
            bl1 = *(const f16x8*)(q1l + (size_t)kn * 4096 + 512);
            int koff = kst * 16 + q * 8;
            f16x8 ah = *(const f16x8*)(sm + ln31 * 264 + koff);
            f16x8 al = *(const f16x8*)(sm + 8448 + ln31 * 264 + koff);
            acc1a = __builtin_amdgcn_mfma_f32_32x32x16_f16(ah, ch0, acc1a, 0, 0, 0);
            acc1b = __builtin_amdgcn_mfma_f32_32x32x16_f16(ah, ch1, acc1b, 0, 0, 0);
            acc1a = __builtin_amdgcn_mfma_f32_32x32x16_f16(al, ch0, acc1a, 0, 0, 0);
            acc1b = __builtin_amdgcn_mfma_f32_32x32x16_f16(al, ch1, acc1b, 0, 0, 0);
            acc1a = __builtin_amdgcn_mfma_f32_32x32x16_f16(ah, cl0, acc1a, 0, 0, 0);
            acc1b = __builtin_amdgcn_mfma_f32_32x32x16_f16(ah, cl1, acc1b, 0, 0, 0);
        }
    }
    __syncthreads();  // all x reads done; region A becomes h1 planes

    // BN + ReLU epilogue; write h1 hi/lo planes (stride 264).
    {
#pragma unroll
        for (int nt = 0; nt < 2; ++nt) {
            int j = w * 64 + nt * 32 + ln31;
            float sc = gm[j] * rsqrtf(vr[j] + EPS_BN);
            float sh = (b1[j] - mu[j]) * sc + bt[j];
            const f32x16& a = nt ? acc1b : acc1a;
#pragma unroll
            for (int r = 0; r < 16; ++r) {
                int row = (r & 3) + 8 * (r >> 2) + 4 * q;
                float v = a[r] * sc + sh;
                v = v > 0.f ? v : 0.f;
                f16 h = (f16)v;
                sm[row * 264 + j]        = h;
                sm[8448 + row * 264 + j] = (f16)(v - (float)h);
            }
        }
    }
    __syncthreads();  // h1 ready

    // ================= Stage 2: h2 = ReLU(h1 @ W2^T + b2) ===================
    f32x16 acc2a = {};
    f32x16 acc2b = {};
    {
        const f16* q2h = p2h + (size_t)w * 512 + lane * 8;
        const f16* q2l = p2l + (size_t)w * 512 + lane * 8;
        f16x8 bh = *(const f16x8*)(q2h);
        f16x8 bl = *(const f16x8*)(q2l);
#pragma unroll 2
        for (int kst = 0; kst < 16; ++kst) {
            f16x8 cbh = bh, cbl = bl;
            int kn = (kst + 1) & 15;
            bh = *(const f16x8*)(q2h + (size_t)kn * 2048);
            bl = *(const f16x8*)(q2l + (size_t)kn * 2048);
            int koff = kst * 16 + q * 8;
            f16x8 ah = *(const f16x8*)(sm + ln31 * 264 + koff);
            f16x8 al = *(const f16x8*)(sm + 8448 + ln31 * 264 + koff);
            f32x16& acc = (kst & 1) ? acc2b : acc2a;
            acc = __builtin_amdgcn_mfma_f32_32x32x16_f16(ah, cbh, acc, 0, 0, 0);
            acc = __builtin_amdgcn_mfma_f32_32x32x16_f16(al, cbh, acc, 0, 0, 0);
            acc = __builtin_amdgcn_mfma_f32_32x32x16_f16(ah, cbl, acc, 0, 0, 0);
        }
    }
    __syncthreads();  // all h1 reads done -> region A reusable for h2

    // ReLU epilogue -> h2 planes aliased into region A (h2h@0, h2l@4352).
    {
        int j2 = w * 32 + ln31;
        float bias = b2[j2];
#pragma unroll
        for (int r = 0; r < 16; ++r) {
            int row = (r & 3) + 8 * (r >> 2) + 4 * q;
            float v = (acc2a[r] + acc2b[r]) + bias;
            v = v > 0.f ? v : 0.f;
            f16 h = (f16)v;
            sm[row * 136 + j2]        = h;
            sm[4352 + row * 136 + j2] = (f16)(v - (float)h);
        }
    }
    __syncthreads();  // h2 ready

    // ================= Stage 3: z = tanh(h2 @ W3^T + b3) ====================
    if (w < 2) {  // 64 output cols -> waves 0,1 only
        f32x16 acc3a = {};
        f32x16 acc3b = {};
        const f16* q3h = p3h + (size_t)w * 512 + lane * 8;
        const f16* q3l = p3l + (size_t)w * 512 + lane * 8;
        f16x8 bh = *(const f16x8*)(q3h);
        f16x8 bl = *(const f16x8*)(q3l);
#pragma unroll 2
        for (int ks = 0; ks < 8; ++ks) {
            f16x8 cbh = bh, cbl = bl;
            int kn = (ks + 1) & 7;
            bh = *(const f16x8*)(q3h + (size_t)kn * 1024);
            bl = *(const f16x8*)(q3l + (size_t)kn * 1024);
            f16x8 ah = *(const f16x8*)(sm + ln31 * 136 + ks * 16 + q * 8);
            f16x8 al = *(const f16x8*)(sm + 4352 + ln31 * 136 + ks * 16 + q * 8);
            f32x16& acc = (ks & 1) ? acc3b : acc3a;
            acc = __builtin_amdgcn_mfma_f32_32x32x16_f16(ah, cbh, acc, 0, 0, 0);
            acc = __builtin_amdgcn_mfma_f32_32x32x16_f16(al, cbh, acc, 0, 0, 0);
            acc = __builtin_amdgcn_mfma_f32_32x32x16_f16(ah, cbl, acc, 0, 0, 0);
        }
        int j3 = w * 32 + ln31;
        float bias = b3[j3];
#pragma unroll
        for (int r = 0; r < 16; ++r) {
            int row = (r & 3) + 8 * (r >> 2) + 4 * q;
            float zv = tanhf((acc3a[r] + acc3b[r]) + bias);
            f16 h = (f16)zv;
            size_t idx = (size_t)(r0 + row) * EMB_DIM + j3;
            Zh[idx] = h;
            Zl[idx] = (f16)(zv - (float)h);
        }
    }
}

// ---------------------------------------------------------------------------
// Kernel 2: MFMA argmin — R13 structure VERBATIM (best measured 119us;
// score accumulation order is part of the verified numeric contract).
// 128 rows/block, 256 threads (4 waves), grid 512. Wave w owns row-tile w;
// consumes all 4 ct from the shared LDS chunk. Double-buffered
// global_load_lds DMA: stage(ch+1) issued BEFORE compute(ch); barrier
// drains vmcnt. score(r,c) = z_r.e_c - 0.5||e_c||^2, maximized == argmin.
// ---------------------------------------------------------------------------
__global__ __launch_bounds__(256) void k_argmin_mfma(
    const f16* __restrict__ Zh, const f16* __restrict__ Zl,
    const f16* __restrict__ cfh, const f16* __restrict__ cfl,
    const float* __restrict__ norms, int* __restrict__ out) {
    __shared__ __align__(16) f16 sm[32768];  // 64KB: buf b at b*16384 (H), +8192 (L)
    const int tid  = threadIdx.x;
    const int lane = tid & 63;
    const int w    = tid >> 6;      // 0..3 = row-tile
    const int ln31 = lane & 31;
    const int q    = lane >> 5;
    const int r0   = blockIdx.x * 128;

    // z fragments: 8 x 16B per lane, straight from global (row-major Z).
    f16x8 ah[4], al[4];
#pragma unroll
    for (int ks = 0; ks < 4; ++ks) {
        size_t zoff = (size_t)(r0 + w * 32 + ln31) * EMB_DIM + ks * 16 + q * 8;
        ah[ks] = *(const f16x8*)(Zh + zoff);
        al[ks] = *(const f16x8*)(Zl + zoff);
    }

    float bv[16];
    int   bi[16];
#pragma unroll
    for (int i = 0; i < 16; ++i) { bv[i] = -3.4e38f; bi[i] = 0; }

#define STAGE(CH, B) do {                                                     \
        const f16* sH_ = cfh + (size_t)(CH) * 8192;                           \
        const f16* sL_ = cfl + (size_t)(CH) * 8192;                           \
        f16* dH_ = sm + (B) * 16384;                                          \
        f16* dL_ = sm + (B) * 16384 + 8192;                                   \
        _Pragma("unroll")                                                     \
        for (int it_ = 0; it_ < 4; ++it_) {                                   \
            int off_ = (it_ * 256 + tid) * 8;                                 \
            __builtin_amdgcn_global_load_lds(                                 \
                (const __attribute__((address_space(1))) void*)(sH_ + off_),  \
                (__attribute__((address_space(3))) void*)(dH_ + off_),        \
                16, 0, 0);                                                    \
            __builtin_amdgcn_global_load_lds(                                 \
                (const __attribute__((address_space(1))) void*)(sL_ + off_),  \
                (__attribute__((address_space(3))) void*)(dL_ + off_),        \
                16, 0, 0);                                                    \
        }                                                                     \
    } while (0)

    STAGE(0, 0);
    __syncthreads();   // prologue: buf0 ready (barrier drains vmcnt)

#pragma unroll 1
    for (int ch = 0; ch < 32; ++ch) {
        int b = ch & 1;
        if (ch + 1 < 32) STAGE(ch + 1, b ^ 1);   // DMA lands under compute
        const f16* ebh = sm + b * 16384;
        const f16* ebl = sm + b * 16384 + 8192;
#pragma unroll 2
        for (int ct = 0; ct < 4; ++ct) {
            f16x8 bh[4], bl[4];
#pragma unroll
            for (int ks = 0; ks < 4; ++ks) {
                int off = (ks * 4 + ct) * 512 + lane * 8;
                bh[ks] = *(const f16x8*)(ebh + off);
                bl[ks] = *(const f16x8*)(ebl + off);
            }
            f32x16 acc0 = {};
            f32x16 acc1 = {};
#pragma unroll
            for (int ks = 0; ks < 4; ks += 2) {
                acc0 = __builtin_amdgcn_mfma_f32_32x32x16_f16(ah[ks],     bh[ks],     acc0, 0, 0, 0);
                acc1 = __builtin_amdgcn_mfma_f32_32x32x16_f16(ah[ks + 1], bh[ks + 1], acc1, 0, 0, 0);
                acc0 = __builtin_amdgcn_mfma_f32_32x32x16_f16(al[ks],     bh[ks],     acc0, 0, 0, 0);
                acc1 = __builtin_amdgcn_mfma_f32_32x32x16_f16(al[ks + 1], bh[ks + 1], acc1, 0, 0, 0);
                acc0 = __builtin_amdgcn_mfma_f32_32x32x16_f16(ah[ks],     bl[ks],     acc0, 0, 0, 0);
                acc1 = __builtin_amdgcn_mfma_f32_32x32x16_f16(ah[ks + 1], bl[ks + 1], acc1, 0, 0, 0);
            }
            int   col = ch * 128 + ct * 32 + ln31;
            float nv  = norms[col];
#pragma unroll
            for (int r = 0; r < 16; ++r) {
                float t  = (acc0[r] + acc1[r]) - nv;
                bool  gt = t > bv[r];
                bv[r] = gt ? t : bv[r];
                bi[r] = gt ? col : bi[r];
            }
        }
        __syncthreads();  // drains vmcnt: buf^1 ready, buf free for re-stage
    }
#undef STAGE

    // ---- cross-lane reduction over 32 code-columns ------------------------
    float* redv = (float*)sm;                // [128][33] f32, bytes [0,16896)
    int*   redi = (int*)sm + 4224;           // [128][33] i32, bytes [16896,33792)
#pragma unroll
    for (int r = 0; r < 16; ++r) {
        int row = w * 32 + (r & 3) + 8 * (r >> 2) + 4 * q;
        redv[row * 33 + ln31] = bv[r];
        redi[row * 33 + ln31] = bi[r];
    }
    __syncthreads();
    if (tid < 128) {
        float v  = redv[tid * 33];
        int   ix = redi[tid * 33];
#pragma unroll
        for (int j = 1; j < 32; ++j) {
            float vj = redv[tid * 33 + j];
            int   ij = redi[tid * 33 + j];
            if (vj > v || (vj == v && ij < ix)) { v = vj; ix = ij; }
        }
        out[r0 + tid] = ix;
    }
}

// ---------------------------------------------------------------------------
extern "C" void kernel_launch(void* const* d_in, const int* in_sizes, int n_in,
                              void* d_out, int out_size, void* d_ws, size_t ws_size,
                              hipStream_t stream) {
    (void)n_in; (void)out_size; (void)ws_size;
    const float* x  = (const float*)d_in[0];
    const float* W1 = (const float*)d_in[1];
    const float* b1 = (const float*)d_in[2];
    const float* gm = (const float*)d_in[3];
    const float* bt = (const float*)d_in[4];
    const float* mu = (const float*)d_in[5];
    const float* vr = (const float*)d_in[6];
    const float* W2 = (const float*)d_in[7];
    const float* b2 = (const float*)d_in[8];
    const float* W3 = (const float*)d_in[9];
    const float* b3 = (const float*)d_in[10];
    const float* cb = (const float*)d_in[11];

    // Workspace layout (~17.4 MB) — same offsets as R6/R7
    char* ws = (char*)d_ws;
    float* norms = (float*)ws;                    // 16 KB
    f16* cfh = (f16*)(ws + 16384);                // 512 KB (cb frags hi)
    f16* cfl = (f16*)(ws + 540672);               // 512 KB (cb frags lo)
    f16* p1h = (f16*)(ws + 1064960);              // 128 KB
    f16* p1l = (f16*)(ws + 1196032);              // 128 KB
    f16* p2h = (f16*)(ws + 1327104);              // 64 KB
    f16* p2l = (f16*)(ws + 1392640);              // 64 KB
    f16* p3h = (f16*)(ws + 1458176);              // 16 KB
    f16* p3l = (f16*)(ws + 1474560);              // 16 KB
    f16* Zh  = (f16*)(ws + 1490944);              // 8 MB
    f16* Zl  = (f16*)(ws + 9879552);              // 8 MB
    int* out = (int*)d_out;

    const int B = in_sizes[0] / IN_DIM;  // 65536

    k_norms<<<K_CODES / 256, 256, 0, stream>>>(cb, norms);
    k_prep<<<180, 256, 0, stream>>>(W1, W2, W3, cb, p1h, p1l, p2h, p2l,
                                    p3h, p3l, cfh, cfl);
    k_encoder_mfma<<<B / 32, 256, 0, stream>>>(x, p1h, p1l, p2h, p2l, p3h, p3l,
                                               b1, gm, bt, mu, vr, b2, b3, Zh, Zl);
    k_argmin_mfma<<<B / 128, 256, 0, stream>>>(Zh, Zl, cfh, cfl, norms, out);
}